// Round 8
// baseline (1760.431 us; speedup 1.0000x reference)
//
#include <hip/hip_runtime.h>
#include <cstddef>
#include <cstdint>

#define TT   32
#define NN   256
#define NLL  16
#define HH   256
#define CONDD 64
#define NEE  8
#define H3   768
#define OW   308

typedef __attribute__((ext_vector_type(8))) short bf16x8;
typedef __attribute__((ext_vector_type(4))) float f32x4;
typedef unsigned short u16;

__device__ __forceinline__ float sigm(float x)     { return 1.f / (1.f + __expf(-x)); }
__device__ __forceinline__ float tanhfast(float x) { return 1.f - 2.f / (__expf(2.f * x) + 1.f); }
__device__ __forceinline__ float bf2f(u16 h) {
    union { unsigned u; float f; } v; v.u = ((unsigned)h) << 16; return v.f;
}
__device__ __forceinline__ u16 f2bf(float f) {   // round-to-nearest-even
    union { float f; unsigned u; } v; v.f = f;
    unsigned r = v.u + 0x7fffu + ((v.u >> 16) & 1u);
    return (u16)(r >> 16);
}
__device__ __forceinline__ bf16x8 pack8(float4 f0, float4 f1) {
    union { u16 u[8]; bf16x8 v; } r;
    r.u[0] = f2bf(f0.x); r.u[1] = f2bf(f0.y); r.u[2] = f2bf(f0.z); r.u[3] = f2bf(f0.w);
    r.u[4] = f2bf(f1.x); r.u[5] = f2bf(f1.y); r.u[6] = f2bf(f1.z); r.u[7] = f2bf(f1.w);
    return r.v;
}
#define MFMA(a, b, c) __builtin_amdgcn_mfma_f32_16x16x32_bf16(a, b, c, 0, 0, 0)

// ---- async global->LDS staging (T3/T4, depth-2) -----------------------------
__device__ __forceinline__ void gl_lds16(const u16* g, u16* l) {
    __builtin_amdgcn_global_load_lds(
        (const __attribute__((address_space(1))) unsigned int*)(const void*)g,
        (__attribute__((address_space(3))) unsigned int*)(void*)l, 16, 0, 0);
}
// Stage one 64-col chunk (32KB) of a [768][256] bf16 matrix into LDS.
// Linear LDS dest; SOURCE granule pre-swizzled (gs ^ (ric&7)) so the swizzled
// ds_read_b128 on the consumer side is conflict-free (same involution).
__device__ __forceinline__ void stage32k(const u16* __restrict__ W, u16* buf,
                                         int c, int w, int lane) {
#pragma unroll
    for (int r = 0; r < 4; ++r) {
        int gran = (w * 4 + r) * 64 + lane;   // 0..2047 granules (16B each)
        int ric = gran >> 5, gs = gran & 31;  // row-in-chunk, granule-in-row
        const u16* src = W + ((size_t)(c * 64 + ric) << 8) + ((gs ^ (ric & 7)) << 3);
        gl_lds16(src, buf + ((w * 4 + r) << 9));   // wave-uniform LDS base
    }
}
__device__ __forceinline__ void wait_vm8()   { asm volatile("s_waitcnt vmcnt(8)" ::: "memory"); }
__device__ __forceinline__ void wait_vm4()   { asm volatile("s_waitcnt vmcnt(4)" ::: "memory"); }
__device__ __forceinline__ void wait_vm0()   { asm volatile("s_waitcnt vmcnt(0)" ::: "memory"); }
__device__ __forceinline__ void wait_lgkm0() { asm volatile("s_waitcnt lgkmcnt(0)" ::: "memory"); }
__device__ __forceinline__ void bar() {
    asm volatile("" ::: "memory");
    __builtin_amdgcn_s_barrier();
    asm volatile("" ::: "memory");
}

// One pipelined chunk: stage chunk C+2, counted wait, barrier, 16 MFMAs into
// two NAMED accumulators (compile-time regs — rule #20), barrier.
// Names in scope: s, SMAX, W, wbuf, w, lane, wn, lm, lg, a[8].
#define CHUNK(C, AA, AB)                                                     \
  {                                                                          \
    if (s != SMAX - 1 || (C) < 10) {                                         \
      stage32k(W, wbuf[((C) + 2) % 3], ((C) + 2) % 12, w, lane);             \
      wait_vm8();                                                            \
    } else if ((C) == 10) { wait_vm4(); } else { wait_vm0(); }               \
    bar();                                                                   \
    {                                                                        \
      const u16* wb_  = wbuf[(C) % 3];                                       \
      const u16* bp0_ = wb_ + (((wn) * 16 + lm) << 8);                       \
      const u16* bp1_ = wb_ + (((2 + wn) * 16 + lm) << 8);                   \
      _Pragma("unroll")                                                      \
      for (int ks = 0; ks < 8; ++ks) {                                       \
        const int off_ = (((ks * 4 + lg) ^ (lm & 7)) << 3);                  \
        AA = MFMA(a[ks], *(const bf16x8*)(bp0_ + off_), AA);                 \
        AB = MFMA(a[ks], *(const bf16x8*)(bp1_ + off_), AB);                 \
      }                                                                      \
    }                                                                        \
    bar();                                                                   \
  }

#define ZERO4(X) { X[0] = 0.f; X[1] = 0.f; X[2] = 0.f; X[3] = 0.f; }

// ---------------------------------------------------------------------------
// Merged fp32 -> bf16 weight casts
// ---------------------------------------------------------------------------
__global__ __launch_bounds__(256) void k_prep(
    const float* __restrict__ gwhh_f, const float* __restrict__ gwhh_b,
    const float* __restrict__ cwhh,  const float* __restrict__ mw1,
    const float* __restrict__ mw2,   const float* __restrict__ w2,
    const float* __restrict__ cwih,
    u16* __restrict__ whhbf_f, u16* __restrict__ whhbf_b, u16* __restrict__ cwhhbf,
    u16* __restrict__ mw1bf, u16* __restrict__ mw2bf, u16* __restrict__ w2bf,
    u16* __restrict__ cwcbf)
{
    long i = (long)blockIdx.x * 256 + threadIdx.x;
    if (i < 196608) { whhbf_f[i] = f2bf(gwhh_f[i]); return; } i -= 196608;
    if (i < 196608) { whhbf_b[i] = f2bf(gwhh_b[i]); return; } i -= 196608;
    if (i < 196608) { cwhhbf[i]  = f2bf(cwhh[i]);  return; } i -= 196608;
    if (i < 65536)  { mw1bf[i]   = f2bf(mw1[i]);   return; } i -= 65536;
    if (i < 65536)  { mw2bf[i]   = f2bf(mw2[i]);   return; } i -= 65536;
    if (i < 4096)   { long r = i >> 8, c = i & 255;
                      w2bf[i] = (r < 8) ? f2bf(w2[r * 256 + c]) : (u16)0; return; } i -= 4096;
    if (i < 49152)  { long r = i >> 6, c = i & 63; cwcbf[i] = f2bf(cwih[r * 320 + c]); }
}

// ---------------------------------------------------------------------------
// Per-token gi tables via MFMA (biases folded; gbhh/cbhh r,z parts folded too)
// ---------------------------------------------------------------------------
__global__ __launch_bounds__(256) void k_tok(
    const float* __restrict__ embed,
    const float* __restrict__ gwih_f, const float* __restrict__ gbih_f, const float* __restrict__ gbhh_f,
    const float* __restrict__ gwih_b, const float* __restrict__ gbih_b, const float* __restrict__ gbhh_b,
    const float* __restrict__ cwih,   const float* __restrict__ cbih,   const float* __restrict__ cbhh,
    u16* __restrict__ gif, u16* __restrict__ gib, u16* __restrict__ gic)
{
    const int mat = blockIdx.x / 6, ch = blockIdx.x % 6;
    const int tid = threadIdx.x, lane = tid & 63, w = tid >> 6;
    const int lm = lane & 15, lg = lane >> 4;
    const float *W, *b1, *b2v; int wstride, woff; u16* dst;
    if (mat == 0)      { W = gwih_f; b1 = gbih_f; b2v = gbhh_f; wstride = 256; woff = 0;  dst = gif; }
    else if (mat == 1) { W = gwih_b; b1 = gbih_b; b2v = gbhh_b; wstride = 256; woff = 0;  dst = gib; }
    else               { W = cwih;   b1 = cbih;   b2v = cbhh;   wstride = 320; woff = 64; dst = gic; }

    bf16x8 a[8];
    #pragma unroll
    for (int ks = 0; ks < 8; ++ks) {
        const float* ep = embed + (size_t)(w * 16 + lm) * 256 + ks * 32 + lg * 8;
        a[ks] = pack8(*(const float4*)ep, *(const float4*)(ep + 4));
    }
    f32x4 acc[8];
    #pragma unroll
    for (int nt = 0; nt < 8; ++nt)
        #pragma unroll
        for (int z = 0; z < 4; ++z) acc[nt][z] = 0.f;

    #pragma unroll
    for (int nt = 0; nt < 8; ++nt) {
        int col = ch * 128 + nt * 16 + lm;
        const float* wp = W + (size_t)col * wstride + woff;
        #pragma unroll
        for (int ks = 0; ks < 8; ++ks) {
            bf16x8 b = pack8(*(const float4*)(wp + ks * 32 + lg * 8),
                             *(const float4*)(wp + ks * 32 + lg * 8 + 4));
            acc[nt] = MFMA(a[ks], b, acc[nt]);
        }
    }
    #pragma unroll
    for (int nt = 0; nt < 8; ++nt) {
        int col = ch * 128 + nt * 16 + lm;
        float bias = b1[col] + (col < 512 ? b2v[col] : 0.f);
        #pragma unroll
        for (int j = 0; j < 4; ++j) {
            int v = w * 16 + lg * 4 + j;
            dst[(size_t)v * H3 + col] = f2bf(acc[nt][j] + bias);
        }
    }
}

// ---------------------------------------------------------------------------
// w-trajectory + out[.,.,0..2] + tok_used
// ---------------------------------------------------------------------------
__global__ void k_wtraj(const int* __restrict__ actions, const int* __restrict__ w0,
                        const int* __restrict__ lines,
                        float* __restrict__ out, int* __restrict__ w_used,
                        int* __restrict__ tok_used)
{
    int n = threadIdx.x;
    int w = w0[n];
    for (int t = 0; t < TT; ++t) {
        int A = actions[((size_t)t * NN + n) * 2 + 0];
        int W = actions[((size_t)t * NN + n) * 2 + 1];
        w_used[t * NN + n] = w;
        tok_used[t * NN + n] = lines[n * NLL + w];
        int wn = w + W - NLL;
        wn = wn < 0 ? 0 : (wn > NLL - 1 ? NLL - 1 : wn);
        float* o = out + ((size_t)t * NN + n) * OW;
        o[0] = (float)A; o[1] = (float)W; o[2] = (float)wn;
        w = wn;
    }
}

// ---------------------------------------------------------------------------
// gi_full[t*256+n][col] = bf16( cond[t,n] @ cwc^T[col] + gic[tok_used[t,n]][col] )
// ---------------------------------------------------------------------------
__global__ __launch_bounds__(256) void k_cg(
    const float* __restrict__ condition, const u16* __restrict__ cwcbf,
    const u16* __restrict__ gic, const int* __restrict__ tok_used,
    u16* __restrict__ gi_full)
{
    const int r0 = blockIdx.x * 32;
    const int tid = threadIdx.x, lane = tid & 63, w = tid >> 6;
    const int wm = w >> 1, wn = w & 1;
    const int lm = lane & 15, lg = lane >> 4;

    bf16x8 a[2];
    #pragma unroll
    for (int ks = 0; ks < 2; ++ks) {
        const float* cp = condition + (size_t)(r0 + wm * 16 + lm) * 64 + ks * 32 + lg * 8;
        a[ks] = pack8(*(const float4*)cp, *(const float4*)(cp + 4));
    }
    f32x4 acc[24];
    #pragma unroll
    for (int jj = 0; jj < 24; ++jj)
        #pragma unroll
        for (int z = 0; z < 4; ++z) acc[jj][z] = 0.f;

    #pragma unroll
    for (int jj = 0; jj < 24; ++jj) {
        int tile = 2 * jj + wn;
        const u16* bp = cwcbf + (size_t)(tile * 16 + lm) * 64;
        #pragma unroll
        for (int ks = 0; ks < 2; ++ks)
            acc[jj] = MFMA(a[ks], *(const bf16x8*)(bp + ks * 32 + lg * 8), acc[jj]);
    }
    int wv[4];
    #pragma unroll
    for (int j = 0; j < 4; ++j) wv[j] = tok_used[r0 + wm * 16 + lg * 4 + j];
    #pragma unroll
    for (int jj = 0; jj < 24; ++jj) {
        int col = (2 * jj + wn) * 16 + lm;
        #pragma unroll
        for (int j = 0; j < 4; ++j) {
            int g = r0 + wm * 16 + lg * 4 + j;
            float v = acc[jj][j] + bf2f(gic[(size_t)wv[j] * H3 + col]);
            gi_full[(size_t)g * H3 + col] = f2bf(v);
        }
    }
}

// ---------------------------------------------------------------------------
// GRU: 128 blocks x 512 thr, 64 rows/block, 16 steps.
// Depth-2 pipeline, 12 chunks x 64 cols (32KB), 3 LDS buffers, counted vmcnt.
// All accumulators NAMED (compile-time register residency — rule #20).
// ---------------------------------------------------------------------------
__global__ __launch_bounds__(512, 2) void k_gru(
    const u16* __restrict__ whhbf_f, const u16* __restrict__ whhbf_b,
    const u16* __restrict__ gif, const u16* __restrict__ gib,
    const float* __restrict__ gbhh_f, const float* __restrict__ gbhh_b,
    const u16* __restrict__ w2bf, const float* __restrict__ b2,
    float* __restrict__ Bf, float* __restrict__ Bb,
    const int* __restrict__ lines)
{
    __shared__ __align__(16) u16 hlds[64 * 264];      // 33.8 KB
    __shared__ __align__(16) u16 wbuf_s[3][64 * 256]; // 96 KB (3 x 32KB)
    __shared__ __align__(16) u16 w2l[4096];           // 8 KB
    __shared__ int lns[1024];                         // 4 KB
    u16* wbuf[3] = { wbuf_s[0], wbuf_s[1], wbuf_s[2] };

    const int tid = threadIdx.x, lane = tid & 63, w = tid >> 6;
    const int lm = lane & 15, lg = lane >> 4;
    const int wm = w >> 1, wn = w & 1;
    const int bid = blockIdx.x;
    const int dir = bid >> 6, lb = bid & 63;
    const int ii = lb >> 2, nb = (lb & 3) << 6;
    const u16*   W    = dir ? whhbf_b : whhbf_f;
    const u16*   git  = dir ? gib : gif;
    const float* bhhs = dir ? gbhh_b : gbhh_f;
    float*       Bout = dir ? Bb : Bf;
    const int SMAX = 16;

    float bn[8];
    #pragma unroll
    for (int jr = 0; jr < 8; ++jr) bn[jr] = bhhs[512 + (2 * jr + wn) * 16 + lm];
    const float b2e = (lm < 8) ? b2[lm] : 0.f;

    for (int k = tid; k < 64 * 264; k += 512) hlds[k] = 0;
    float hreg[32];
    #pragma unroll
    for (int k = 0; k < 32; ++k) hreg[k] = 0.f;
    for (int k = tid; k < 1024; k += 512)
        lns[k] = lines[(nb + (k >> 4)) * NLL + (k & 15)];
    for (int k = tid; k < 4096; k += 512) w2l[k] = w2bf[k];
    __syncthreads();

    bf16x8 a[8];
    #pragma unroll
    for (int ks = 0; ks < 8; ++ks)
        a[ks] = *(const bf16x8*)&hlds[(wm * 16 + lm) * 264 + ks * 32 + lg * 8];

    stage32k(W, wbuf[0], 0, w, lane);      // prologue: chunks 0,1 in flight
    stage32k(W, wbuf[1], 1, w, lane);

    for (int s = 0; s < SMAX; ++s) {
        f32x4 A0, A1, A2, A3, A4, A5, A6, A7, A8, A9, A10, A11,
              A12, A13, A14, A15, A16, A17, A18, A19, A20, A21, A22, A23;
        ZERO4(A0)  ZERO4(A1)  ZERO4(A2)  ZERO4(A3)  ZERO4(A4)  ZERO4(A5)
        ZERO4(A6)  ZERO4(A7)  ZERO4(A8)  ZERO4(A9)  ZERO4(A10) ZERO4(A11)
        ZERO4(A12) ZERO4(A13) ZERO4(A14) ZERO4(A15) ZERO4(A16) ZERO4(A17)
        ZERO4(A18) ZERO4(A19) ZERO4(A20) ZERO4(A21) ZERO4(A22) ZERO4(A23)

        CHUNK(0,  A0,  A1)  CHUNK(1,  A2,  A3)  CHUNK(2,  A4,  A5)
        CHUNK(3,  A6,  A7)  CHUNK(4,  A8,  A9)  CHUNK(5,  A10, A11)
        CHUNK(6,  A12, A13) CHUNK(7,  A14, A15) CHUNK(8,  A16, A17)
        CHUNK(9,  A18, A19) CHUNK(10, A20, A21) CHUNK(11, A22, A23)

        // gate phase (A{jr}=r, A{8+jr}=z, A{16+jr}=n for col (2jr+wn)*16+lm)
        const int jpos = dir ? (15 - s) : s;
        const int jt = (ii + jpos) & 15;
#define GGATE(JR, AR, AZ, AN)                                                \
        {                                                                    \
            const int col_ = (2 * (JR) + wn) * 16 + lm;                      \
            _Pragma("unroll")                                                \
            for (int j = 0; j < 4; ++j) {                                    \
                const int lrow_ = wm * 16 + lg * 4 + j;                      \
                const int tok_ = lns[lrow_ * 16 + jt];                       \
                const u16* gi_ = git + (size_t)tok_ * H3;                    \
                float rg_ = sigm(bf2f(gi_[col_]) + AR[j]);                   \
                float zg_ = sigm(bf2f(gi_[col_ + 256]) + AZ[j]);             \
                float ng_ = tanhfast(bf2f(gi_[col_ + 512])                   \
                                     + rg_ * (AN[j] + bn[JR]));              \
                float hv_ = (1.f - zg_) * ng_ + zg_ * hreg[(JR) * 4 + j];    \
                hreg[(JR) * 4 + j] = hv_;                                    \
                hlds[lrow_ * 264 + col_] = f2bf(hv_);                        \
            }                                                                \
        }
        GGATE(0, A0, A8,  A16) GGATE(1, A1, A9,  A17)
        GGATE(2, A2, A10, A18) GGATE(3, A3, A11, A19)
        GGATE(4, A4, A12, A20) GGATE(5, A5, A13, A21)
        GGATE(6, A6, A14, A22) GGATE(7, A7, A15, A23)
#undef GGATE
        wait_lgkm0(); bar();

        // reload A-frags (h_new) + fused B projection via MFMA
        #pragma unroll
        for (int ks = 0; ks < 8; ++ks)
            a[ks] = *(const bf16x8*)&hlds[(wm * 16 + lm) * 264 + ks * 32 + lg * 8];
        {
            f32x4 accB; ZERO4(accB)
            #pragma unroll
            for (int ks = 0; ks < 8; ++ks) {
                bf16x8 wf = *(const bf16x8*)&w2l[lm * 256 + ks * 32 + lg * 8];
                accB = MFMA(a[ks], wf, accB);
            }
            if (lm < 8) {
                #pragma unroll
                for (int j = 0; j < 4; ++j) {
                    int nn = nb + wm * 16 + lg * 4 + j;
                    Bout[(((size_t)ii * NN + nn) * NLL + jpos) * NEE + lm] = sigm(accB[j] + b2e);
                }
            }
        }
    }
}

// ---------------------------------------------------------------------------
// Controller: 4 blocks x 512 thr, 64 rows/block, 32 steps. Same pipeline;
// gate inputs from gi_full (token+cond+biases precomputed). Runs AFTER k_gru.
// ---------------------------------------------------------------------------
__global__ __launch_bounds__(512, 2) void k_ctrl(
    const u16* __restrict__ cwhhbf, const u16* __restrict__ gi_full,
    const float* __restrict__ cbhh, const float* __restrict__ h0,
    u16* __restrict__ Hallbf, float* __restrict__ out)
{
    __shared__ __align__(16) u16 hlds[64 * 264];      // 33.8 KB
    __shared__ __align__(16) u16 wbuf_s[3][64 * 256]; // 96 KB
    u16* wbuf[3] = { wbuf_s[0], wbuf_s[1], wbuf_s[2] };

    const int tid = threadIdx.x, lane = tid & 63, w = tid >> 6;
    const int lm = lane & 15, lg = lane >> 4;
    const int wm = w >> 1, wn = w & 1;
    const int cb = blockIdx.x;                        // rows cb*64..+64
    const u16* W = cwhhbf;
    const int SMAX = TT;

    float bn[8];
    #pragma unroll
    for (int jr = 0; jr < 8; ++jr) bn[jr] = cbhh[512 + (2 * jr + wn) * 16 + lm];

    float hreg[32];
    #pragma unroll
    for (int jr = 0; jr < 8; ++jr) {
        int col = (2 * jr + wn) * 16 + lm;
        #pragma unroll
        for (int j = 0; j < 4; ++j) {
            int lrow = wm * 16 + lg * 4 + j;
            float hv = h0[(size_t)(cb * 64 + lrow) * HH + col];
            hreg[jr * 4 + j] = hv;
            hlds[lrow * 264 + col] = f2bf(hv);
        }
    }
    __syncthreads();

    bf16x8 a[8];
    #pragma unroll
    for (int ks = 0; ks < 8; ++ks)
        a[ks] = *(const bf16x8*)&hlds[(wm * 16 + lm) * 264 + ks * 32 + lg * 8];

    stage32k(W, wbuf[0], 0, w, lane);
    stage32k(W, wbuf[1], 1, w, lane);

    for (int s = 0; s < SMAX; ++s) {
        f32x4 A0, A1, A2, A3, A4, A5, A6, A7, A8, A9, A10, A11,
              A12, A13, A14, A15, A16, A17, A18, A19, A20, A21, A22, A23;
        ZERO4(A0)  ZERO4(A1)  ZERO4(A2)  ZERO4(A3)  ZERO4(A4)  ZERO4(A5)
        ZERO4(A6)  ZERO4(A7)  ZERO4(A8)  ZERO4(A9)  ZERO4(A10) ZERO4(A11)
        ZERO4(A12) ZERO4(A13) ZERO4(A14) ZERO4(A15) ZERO4(A16) ZERO4(A17)
        ZERO4(A18) ZERO4(A19) ZERO4(A20) ZERO4(A21) ZERO4(A22) ZERO4(A23)

        CHUNK(0,  A0,  A1)  CHUNK(1,  A2,  A3)  CHUNK(2,  A4,  A5)
        CHUNK(3,  A6,  A7)  CHUNK(4,  A8,  A9)  CHUNK(5,  A10, A11)
        CHUNK(6,  A12, A13) CHUNK(7,  A14, A15) CHUNK(8,  A16, A17)
        CHUNK(9,  A18, A19) CHUNK(10, A20, A21) CHUNK(11, A22, A23)

#define CGATE(JR, AR, AZ, AN)                                                \
        {                                                                    \
            const int col_ = (2 * (JR) + wn) * 16 + lm;                      \
            _Pragma("unroll")                                                \
            for (int j = 0; j < 4; ++j) {                                    \
                const int lrow_ = wm * 16 + lg * 4 + j;                      \
                const size_t g_ = (size_t)s * NN + cb * 64 + lrow_;          \
                const u16* gi_ = gi_full + g_ * H3;                          \
                float rg_ = sigm(bf2f(gi_[col_]) + AR[j]);                   \
                float zg_ = sigm(bf2f(gi_[col_ + 256]) + AZ[j]);             \
                float ng_ = tanhfast(bf2f(gi_[col_ + 512])                   \
                                     + rg_ * (AN[j] + bn[JR]));              \
                float hv_ = (1.f - zg_) * ng_ + zg_ * hreg[(JR) * 4 + j];    \
                hreg[(JR) * 4 + j] = hv_;                                    \
                hlds[lrow_ * 264 + col_] = f2bf(hv_);                        \
                out[g_ * OW + 4 + col_] = hv_;                               \
                Hallbf[g_ * HH + col_] = f2bf(hv_);                          \
            }                                                                \
        }
        CGATE(0, A0, A8,  A16) CGATE(1, A1, A9,  A17)
        CGATE(2, A2, A10, A18) CGATE(3, A3, A11, A19)
        CGATE(4, A4, A12, A20) CGATE(5, A5, A13, A21)
        CGATE(6, A6, A14, A22) CGATE(7, A7, A15, A23)
#undef CGATE
        wait_lgkm0(); bar();

        #pragma unroll
        for (int ks = 0; ks < 8; ++ks)
            a[ks] = *(const bf16x8*)&hlds[(wm * 16 + lm) * 264 + ks * 32 + lg * 8];
    }
}

// ---------------------------------------------------------------------------
// Stick-breaking + reversals + roll into final P layout (verified)
// ---------------------------------------------------------------------------
__global__ __launch_bounds__(256) void k_stick(
    const float* __restrict__ Bf, const float* __restrict__ Bb,
    float* __restrict__ P_final)
{
    int idx = blockIdx.x * 256 + threadIdx.x;
    if (idx >= 16 * 256 * 8) return;
    int e = idx & 7, n = (idx >> 3) & 255, i = idx >> 11;
    const float* bf = Bf + ((size_t)(i * NN + n) * NLL) * NEE + e;
    const float* bb = Bb + ((size_t)(i * NN + n) * NLL) * NEE + e;
    int i2 = (i + 15) & 15;
    float* dst = P_final + ((size_t)(i2 * NN + n) * 32) * NEE + e;
    float cum = 1.f;
    #pragma unroll
    for (int m = 0; m < 16; ++m) {
        float c0 = bf[m * NEE];
        float c1 = bb[(15 - m) * NEE];
        float v0 = c0 * cum;
        cum *= (1.f - c0);
        float v1 = (m < 15) ? c1 * cum : cum;
        cum *= (1.f - c1);
        dst[(size_t)(((17 + m) & 31)) * NEE] = v0;
        dst[(size_t)((16 - m)) * NEE]        = v1;
    }
}

// ---------------------------------------------------------------------------
// Batched MLP layer: Out = bf16(relu(A @ W^T + bias)), A (8192,256) bf16
// ---------------------------------------------------------------------------
__global__ __launch_bounds__(256) void k_mlp(
    const u16* __restrict__ A, const u16* __restrict__ W,
    const float* __restrict__ bias, u16* __restrict__ Out)
{
    __shared__ u16 ot[32 * 264];
    const int g0 = blockIdx.x * 32;
    const int tid = threadIdx.x, lane = tid & 63, w = tid >> 6;
    const int lm = lane & 15, lg = lane >> 4;
    f32x4 acc[4][2];
    #pragma unroll
    for (int c = 0; c < 4; ++c)
        #pragma unroll
        for (int r = 0; r < 2; ++r)
            #pragma unroll
            for (int z = 0; z < 4; ++z) acc[c][r][z] = 0.f;
    #pragma unroll
    for (int ks = 0; ks < 8; ++ks) {
        bf16x8 a0 = *(const bf16x8*)&A[(size_t)(g0 + lm) * 256 + ks * 32 + lg * 8];
        bf16x8 a1 = *(const bf16x8*)&A[(size_t)(g0 + 16 + lm) * 256 + ks * 32 + lg * 8];
        #pragma unroll
        for (int cf = 0; cf < 4; ++cf) {
            const u16* bp = W + (size_t)(w * 64 + cf * 16 + lm) * 256 + ks * 32 + lg * 8;
            bf16x8 b = *(const bf16x8*)bp;
            acc[cf][0] = MFMA(a0, b, acc[cf][0]);
            acc[cf][1] = MFMA(a1, b, acc[cf][1]);
        }
    }
    #pragma unroll
    for (int cf = 0; cf < 4; ++cf) {
        int col = w * 64 + cf * 16 + lm;
        float bs = bias[col];
        #pragma unroll
        for (int rf = 0; rf < 2; ++rf)
            #pragma unroll
            for (int j = 0; j < 4; ++j) {
                int lrow = rf * 16 + lg * 4 + j;
                ot[lrow * 264 + col] = f2bf(fmaxf(acc[cf][rf][j] + bs, 0.f));
            }
    }
    __syncthreads();
    int lrow = tid >> 3, c0 = (tid & 7) * 32;
    const uint4* src = (const uint4*)&ot[lrow * 264 + c0];
    uint4* dst = (uint4*)&Out[(size_t)(g0 + lrow) * 256 + c0];
    dst[0] = src[0]; dst[1] = src[1]; dst[2] = src[2]; dst[3] = src[3];
}

// ---------------------------------------------------------------------------
// Heads: 25 logits per row + softmaxes + v + p_probs
// ---------------------------------------------------------------------------
__global__ __launch_bounds__(256) void k_heads(
    const u16* __restrict__ zbf,
    const float* __restrict__ aw, const float* __restrict__ ab,
    const float* __restrict__ ow, const float* __restrict__ ob,
    const float* __restrict__ cw, const float* __restrict__ cb,
    const float* __restrict__ P_final, const int* __restrict__ w_used,
    float* __restrict__ out)
{
    __shared__ float zt[32 * 258];
    __shared__ float hd[32][28];
    __shared__ float o8[32][8];
    __shared__ int   wv[32];
    const int g0 = blockIdx.x * 32, tid = threadIdx.x;
    {
        int lrow = tid >> 3, c0 = (tid & 7) * 32;
        const u16* src = &zbf[(size_t)(g0 + lrow) * 256 + c0];
        #pragma unroll
        for (int k = 0; k < 32; ++k) zt[lrow * 258 + c0 + k] = bf2f(src[k]);
    }
    if (tid < 32) wv[tid] = w_used[g0 + tid];
    __syncthreads();
    {
        int r = tid >> 3, s = tid & 7;
        const float* z = &zt[r * 258];
        float a1 = ab[s], a2 = ab[8 + s], a3 = ob[s], a4 = cb[0];
        const float* w1 = aw + s * 256;
        const float* w2_ = aw + (8 + s) * 256;
        const float* w3 = ow + s * 256;
        for (int c = 0; c < 256; ++c) {
            float zv = z[c];
            a1 += zv * w1[c]; a2 += zv * w2_[c]; a3 += zv * w3[c]; a4 += zv * cw[c];
        }
        hd[r][s] = a1; hd[r][8 + s] = a2; hd[r][16 + s] = a3;
        if (s == 0) hd[r][24] = a4;
    }
    __syncthreads();
    if (tid < 32) {
        int r = tid; int g = g0 + r;
        float* orow = out + (size_t)g * OW;
        float mx = hd[r][0];
        #pragma unroll
        for (int k = 1; k < 16; ++k) mx = fmaxf(mx, hd[r][k]);
        float ex[16], ssum = 0.f;
        #pragma unroll
        for (int k = 0; k < 16; ++k) { ex[k] = __expf(hd[r][k] - mx); ssum += ex[k]; }
        float inv = 1.f / ssum;
        #pragma unroll
        for (int k = 0; k < 16; ++k) orow[260 + k] = ex[k] * inv;
        orow[3] = hd[r][24];
        float mo = hd[r][16];
        #pragma unroll
        for (int k = 1; k < 8; ++k) mo = fmaxf(mo, hd[r][16 + k]);
        float eo[8], so = 0.f;
        #pragma unroll
        for (int k = 0; k < 8; ++k) { eo[k] = __expf(hd[r][16 + k] - mo); so += eo[k]; }
        float invo = 1.f / so;
        #pragma unroll
        for (int k = 0; k < 8; ++k) o8[r][k] = eo[k] * invo;
    }
    __syncthreads();
    {
        int r = tid >> 3, kb = tid & 7;
        int g = g0 + r, n = g & 255;
        const float* base = P_final + ((size_t)(wv[r] * NN + n) * 32) * NEE;
        float* orow = out + (size_t)g * OW + 276;
        #pragma unroll
        for (int m = 0; m < 4; ++m) {
            int k = kb + m * 8;
            const float* pe = base + k * NEE;
            float a = 0.f;
            #pragma unroll
            for (int e = 0; e < 8; ++e) a += pe[e] * o8[r][e];
            orow[k] = a;
        }
    }
}

// ---------------------------------------------------------------------------
extern "C" void kernel_launch(void* const* d_in, const int* in_sizes, int n_in,
                              void* d_out, int out_size, void* d_ws, size_t ws_size,
                              hipStream_t stream) {
    const float* condition = (const float*)d_in[0];
    const int*   lines     = (const int*)  d_in[1];
    const int*   actions   = (const int*)  d_in[2];
    const float* h0        = (const float*)d_in[3];
    const int*   w0        = (const int*)  d_in[4];
    const float* embed     = (const float*)d_in[5];
    const float* gwih_f    = (const float*)d_in[6];
    const float* gwhh_f    = (const float*)d_in[7];
    const float* gbih_f    = (const float*)d_in[8];
    const float* gbhh_f    = (const float*)d_in[9];
    const float* gwih_b    = (const float*)d_in[10];
    const float* gwhh_b    = (const float*)d_in[11];
    const float* gbih_b    = (const float*)d_in[12];
    const float* gbhh_b    = (const float*)d_in[13];
    const float* w2        = (const float*)d_in[14];
    const float* b2        = (const float*)d_in[15];
    const float* cwih      = (const float*)d_in[16];
    const float* cwhh      = (const float*)d_in[17];
    const float* cbih      = (const float*)d_in[18];
    const float* cbhh      = (const float*)d_in[19];
    const float* mw1       = (const float*)d_in[20];
    const float* mb1       = (const float*)d_in[21];
    const float* mw2       = (const float*)d_in[22];
    const float* mb2       = (const float*)d_in[23];
    const float* ow        = (const float*)d_in[24];
    const float* ob        = (const float*)d_in[25];
    const float* aw        = (const float*)d_in[26];
    const float* ab        = (const float*)d_in[27];
    const float* cw        = (const float*)d_in[28];
    const float* cb        = (const float*)d_in[29];
    float* out = (float*)d_out;

    // workspace carve-up (~23 MB, aliased)
    char* base = (char*)d_ws;
    auto alloc = [&](size_t bytes) { char* r = base; base += (bytes + 255) & ~(size_t)255; return r; };
    u16*   gif_tok = (u16*)alloc(64 * H3 * 2);
    u16*   gib_tok = (u16*)alloc(64 * H3 * 2);
    u16*   gic_tok = (u16*)alloc(64 * H3 * 2);
    u16*   whhbf_f = (u16*)alloc(H3 * 256 * 2);
    u16*   whhbf_b = (u16*)alloc(H3 * 256 * 2);
    u16*   cwhhbf  = (u16*)alloc(H3 * 256 * 2);
    u16*   mw1bf   = (u16*)alloc(256 * 256 * 2);
    u16*   mw2bf   = (u16*)alloc(256 * 256 * 2);
    u16*   w2bf    = (u16*)alloc(16 * 256 * 2);
    u16*   cwcbf   = (u16*)alloc(H3 * 64 * 2);
    u16*   gi_full = (u16*)alloc((size_t)TT * NN * H3 * 2);   // 12.6 MB
    float* Bf      = (float*)alloc((size_t)16 * 256 * 16 * 8 * 4);
    float* Bb      = (float*)alloc((size_t)16 * 256 * 16 * 8 * 4);
    u16*   Hallbf  = (u16*)alloc((size_t)TT * NN * 256 * 2);
    int*   w_used  = (int*)alloc((size_t)TT * NN * 4);
    int*   tok_used= (int*)alloc((size_t)TT * NN * 4);
    // aliases (dead-after-ctrl / dead-after-stick regions)
    float* P_final = (float*)gi_full;                          // written post-ctrl
    u16*   zbf     = (u16*)((char*)gi_full + (size_t)4 * 1024 * 1024);
    u16*   z1bf    = (u16*)Bf;                                 // after k_stick

    k_prep<<<3024, 256, 0, stream>>>(gwhh_f, gwhh_b, cwhh, mw1, mw2, w2, cwih,
                                     whhbf_f, whhbf_b, cwhhbf, mw1bf, mw2bf, w2bf, cwcbf);

    k_tok<<<18, 256, 0, stream>>>(embed,
                                  gwih_f, gbih_f, gbhh_f,
                                  gwih_b, gbih_b, gbhh_b,
                                  cwih, cbih, cbhh,
                                  gif_tok, gib_tok, gic_tok);

    k_wtraj<<<1, 256, 0, stream>>>(actions, w0, lines, out, w_used, tok_used);

    k_cg<<<256, 256, 0, stream>>>(condition, cwcbf, gic_tok, tok_used, gi_full);

    k_gru<<<128, 512, 0, stream>>>(whhbf_f, whhbf_b, gif_tok, gib_tok, gbhh_f, gbhh_b,
                                   w2bf, b2, Bf, Bb, lines);

    k_ctrl<<<4, 512, 0, stream>>>(cwhhbf, gi_full, cbhh, h0, Hallbf, out);

    k_stick<<<128, 256, 0, stream>>>(Bf, Bb, P_final);

    k_mlp<<<256, 256, 0, stream>>>(Hallbf, mw1bf, mb1, z1bf);
    k_mlp<<<256, 256, 0, stream>>>(z1bf, mw2bf, mb2, zbf);

    k_heads<<<256, 256, 0, stream>>>(zbf, aw, ab, ow, ob, cw, cb, P_final, w_used, out);
}

// Round 9
// 980.600 us; speedup vs baseline: 1.7953x; 1.7953x over previous
//
#include <hip/hip_runtime.h>
#include <cstddef>
#include <cstdint>

#define TT   32
#define NN   256
#define NLL  16
#define HH   256
#define CONDD 64
#define NEE  8
#define H3   768
#define OW   308

typedef __attribute__((ext_vector_type(8))) short bf16x8;
typedef __attribute__((ext_vector_type(4))) float f32x4;
typedef unsigned short u16;

__device__ __forceinline__ float sigm(float x)     { return 1.f / (1.f + __expf(-x)); }
__device__ __forceinline__ float tanhfast(float x) { return 1.f - 2.f / (__expf(2.f * x) + 1.f); }
__device__ __forceinline__ float bf2f(u16 h) {
    union { unsigned u; float f; } v; v.u = ((unsigned)h) << 16; return v.f;
}
__device__ __forceinline__ u16 f2bf(float f) {   // round-to-nearest-even
    union { float f; unsigned u; } v; v.f = f;
    unsigned r = v.u + 0x7fffu + ((v.u >> 16) & 1u);
    return (u16)(r >> 16);
}
__device__ __forceinline__ bf16x8 pack8(float4 f0, float4 f1) {
    union { u16 u[8]; bf16x8 v; } r;
    r.u[0] = f2bf(f0.x); r.u[1] = f2bf(f0.y); r.u[2] = f2bf(f0.z); r.u[3] = f2bf(f0.w);
    r.u[4] = f2bf(f1.x); r.u[5] = f2bf(f1.y); r.u[6] = f2bf(f1.z); r.u[7] = f2bf(f1.w);
    return r.v;
}
#define MFMA(a, b, c) __builtin_amdgcn_mfma_f32_16x16x32_bf16(a, b, c, 0, 0, 0)

// ---- async global->LDS staging --------------------------------------------
__device__ __forceinline__ void gl_lds16(const u16* g, u16* l) {
    __builtin_amdgcn_global_load_lds(
        (const __attribute__((address_space(1))) unsigned int*)(const void*)g,
        (__attribute__((address_space(3))) unsigned int*)(void*)l, 16, 0, 0);
}
// Stage one 24KB chunk (96 rows x 128 K-entries bf16) of the gate-triple
// reordered weight matrix Wr. LDS dest linear; SOURCE 16B-granule pre-swizzled
// (p ^ (q&15)) so the swizzled ds_read_b128 on the consumer side is uniform
// across banks (source perm == read perm, involution). 3 instrs per wave.
__device__ __forceinline__ void stage24k(const u16* __restrict__ Wr, u16* buf,
                                         int c, int w, int lane) {
#pragma unroll
    for (int r = 0; r < 3; ++r) {
        int G = (w * 3 + r) * 64 + lane;   // granule 0..1535
        int q = G >> 4, p = G & 15;        // row-in-chunk, granule-in-row
        const u16* src = Wr + ((size_t)(c * 96 + q) << 7) + ((p ^ (q & 15)) << 3);
        gl_lds16(src, buf + ((w * 3 + r) << 9));   // wave-uniform LDS base
    }
}
__device__ __forceinline__ void wait_vm9()   { asm volatile("s_waitcnt vmcnt(9)" ::: "memory"); }
__device__ __forceinline__ void wait_vm6()   { asm volatile("s_waitcnt vmcnt(6)" ::: "memory"); }
__device__ __forceinline__ void wait_vm3()   { asm volatile("s_waitcnt vmcnt(3)" ::: "memory"); }
__device__ __forceinline__ void wait_vm0()   { asm volatile("s_waitcnt vmcnt(0)" ::: "memory"); }
__device__ __forceinline__ void wait_lgkm0() { asm volatile("s_waitcnt lgkmcnt(0)" ::: "memory"); }
__device__ __forceinline__ void bar() {
    asm volatile("" ::: "memory");
    __builtin_amdgcn_s_barrier();
    asm volatile("" ::: "memory");
}

#define ZERO4(X) { X[0] = 0.f; X[1] = 0.f; X[2] = 0.f; X[3] = 0.f; }

// One pipelined chunk: stage chunk C+3 (if within step), counted wait, bar,
// 12 MFMAs (r,z,n tiles for this wave's 16-col slice, K-half KH), bar.
// In scope: W, wbuf_s, w, lane, wn, lm, lg, a[8].
#define DO_CHUNK(C, KH, AR, AZ, AN)                                          \
  {                                                                          \
    if ((C) <= 12) { stage24k(W, wbuf_s[((C)+3)&3], (C)+3, w, lane); wait_vm9(); } \
    else if ((C) == 13) { wait_vm6(); }                                      \
    else if ((C) == 14) { wait_vm3(); }                                      \
    else { wait_vm0(); }                                                     \
    bar();                                                                   \
    {                                                                        \
      const u16* wb_ = wbuf_s[(C)&3];                                        \
      const int rb_ = wn * 16 + lm;                                          \
      _Pragma("unroll")                                                      \
      for (int k2 = 0; k2 < 4; ++k2) {                                       \
        const int go_ = (((k2 * 4 + lg) ^ lm) << 3);                         \
        AR = MFMA(a[(KH)*4 + k2], *(const bf16x8*)&wb_[(rb_) * 128 + go_], AR); \
        AZ = MFMA(a[(KH)*4 + k2], *(const bf16x8*)&wb_[(32 + rb_) * 128 + go_], AZ); \
        AN = MFMA(a[(KH)*4 + k2], *(const bf16x8*)&wb_[(64 + rb_) * 128 + go_], AN); \
      }                                                                      \
    }                                                                        \
    bar();                                                                   \
  }

// ---------------------------------------------------------------------------
// fp32 -> bf16 weight casts; whh/cwhh go through the gate-triple chunk remap:
// Wr[(c*96+q)*128 + k], c=cg*2+kh, q=g*32+cj  <-  W[(g*256+cg*32+cj)*256+kh*128+k]
// ---------------------------------------------------------------------------
__device__ __forceinline__ long wremap(long i) {
    long k = i & 127, row = i >> 7;
    long c = row / 96, q = row % 96;
    long cg = c >> 1, kh = c & 1;
    long g = q >> 5, cj = q & 31;
    return (g * 256 + cg * 32 + cj) * 256 + kh * 128 + k;
}
__global__ __launch_bounds__(256) void k_prep(
    const float* __restrict__ gwhh_f, const float* __restrict__ gwhh_b,
    const float* __restrict__ cwhh,  const float* __restrict__ mw1,
    const float* __restrict__ mw2,   const float* __restrict__ w2,
    const float* __restrict__ cwih,
    u16* __restrict__ whhr_f, u16* __restrict__ whhr_b, u16* __restrict__ cwhr,
    u16* __restrict__ mw1bf, u16* __restrict__ mw2bf, u16* __restrict__ w2bf,
    u16* __restrict__ cwcbf)
{
    long i = (long)blockIdx.x * 256 + threadIdx.x;
    if (i < 196608) { whhr_f[i] = f2bf(gwhh_f[wremap(i)]); return; } i -= 196608;
    if (i < 196608) { whhr_b[i] = f2bf(gwhh_b[wremap(i)]); return; } i -= 196608;
    if (i < 196608) { cwhr[i]   = f2bf(cwhh[wremap(i)]);   return; } i -= 196608;
    if (i < 65536)  { mw1bf[i]  = f2bf(mw1[i]);   return; } i -= 65536;
    if (i < 65536)  { mw2bf[i]  = f2bf(mw2[i]);   return; } i -= 65536;
    if (i < 4096)   { long r = i >> 8, c = i & 255;
                      w2bf[i] = (r < 8) ? f2bf(w2[r * 256 + c]) : (u16)0; return; } i -= 4096;
    if (i < 49152)  { long r = i >> 6, c = i & 63; cwcbf[i] = f2bf(cwih[r * 320 + c]); }
}

// ---------------------------------------------------------------------------
// Per-token gi tables via MFMA (biases folded; gbhh/cbhh r,z parts folded too)
// ---------------------------------------------------------------------------
__global__ __launch_bounds__(256) void k_tok(
    const float* __restrict__ embed,
    const float* __restrict__ gwih_f, const float* __restrict__ gbih_f, const float* __restrict__ gbhh_f,
    const float* __restrict__ gwih_b, const float* __restrict__ gbih_b, const float* __restrict__ gbhh_b,
    const float* __restrict__ cwih,   const float* __restrict__ cbih,   const float* __restrict__ cbhh,
    u16* __restrict__ gif, u16* __restrict__ gib, u16* __restrict__ gic)
{
    const int mat = blockIdx.x / 6, ch = blockIdx.x % 6;
    const int tid = threadIdx.x, lane = tid & 63, w = tid >> 6;
    const int lm = lane & 15, lg = lane >> 4;
    const float *W, *b1, *b2v; int wstride, woff; u16* dst;
    if (mat == 0)      { W = gwih_f; b1 = gbih_f; b2v = gbhh_f; wstride = 256; woff = 0;  dst = gif; }
    else if (mat == 1) { W = gwih_b; b1 = gbih_b; b2v = gbhh_b; wstride = 256; woff = 0;  dst = gib; }
    else               { W = cwih;   b1 = cbih;   b2v = cbhh;   wstride = 320; woff = 64; dst = gic; }

    bf16x8 a[8];
    #pragma unroll
    for (int ks = 0; ks < 8; ++ks) {
        const float* ep = embed + (size_t)(w * 16 + lm) * 256 + ks * 32 + lg * 8;
        a[ks] = pack8(*(const float4*)ep, *(const float4*)(ep + 4));
    }
    f32x4 acc[8];
    #pragma unroll
    for (int nt = 0; nt < 8; ++nt)
        #pragma unroll
        for (int z = 0; z < 4; ++z) acc[nt][z] = 0.f;

    #pragma unroll
    for (int nt = 0; nt < 8; ++nt) {
        int col = ch * 128 + nt * 16 + lm;
        const float* wp = W + (size_t)col * wstride + woff;
        #pragma unroll
        for (int ks = 0; ks < 8; ++ks) {
            bf16x8 b = pack8(*(const float4*)(wp + ks * 32 + lg * 8),
                             *(const float4*)(wp + ks * 32 + lg * 8 + 4));
            acc[nt] = MFMA(a[ks], b, acc[nt]);
        }
    }
    #pragma unroll
    for (int nt = 0; nt < 8; ++nt) {
        int col = ch * 128 + nt * 16 + lm;
        float bias = b1[col] + (col < 512 ? b2v[col] : 0.f);
        #pragma unroll
        for (int j = 0; j < 4; ++j) {
            int v = w * 16 + lg * 4 + j;
            dst[(size_t)v * H3 + col] = f2bf(acc[nt][j] + bias);
        }
    }
}

// ---------------------------------------------------------------------------
// w-trajectory + out[.,.,0..2] + tok_used
// ---------------------------------------------------------------------------
__global__ void k_wtraj(const int* __restrict__ actions, const int* __restrict__ w0,
                        const int* __restrict__ lines,
                        float* __restrict__ out, int* __restrict__ w_used,
                        int* __restrict__ tok_used)
{
    int n = threadIdx.x;
    int w = w0[n];
    for (int t = 0; t < TT; ++t) {
        int A = actions[((size_t)t * NN + n) * 2 + 0];
        int W = actions[((size_t)t * NN + n) * 2 + 1];
        w_used[t * NN + n] = w;
        tok_used[t * NN + n] = lines[n * NLL + w];
        int wn = w + W - NLL;
        wn = wn < 0 ? 0 : (wn > NLL - 1 ? NLL - 1 : wn);
        float* o = out + ((size_t)t * NN + n) * OW;
        o[0] = (float)A; o[1] = (float)W; o[2] = (float)wn;
        w = wn;
    }
}

// ---------------------------------------------------------------------------
// gi_full[t*256+n][col] = bf16( cond[t,n] @ cwc^T[col] + gic[tok_used[t,n]][col] )
// ---------------------------------------------------------------------------
__global__ __launch_bounds__(256) void k_cg(
    const float* __restrict__ condition, const u16* __restrict__ cwcbf,
    const u16* __restrict__ gic, const int* __restrict__ tok_used,
    u16* __restrict__ gi_full)
{
    const int r0 = blockIdx.x * 32;
    const int tid = threadIdx.x, lane = tid & 63, w = tid >> 6;
    const int wm = w >> 1, wn = w & 1;
    const int lm = lane & 15, lg = lane >> 4;

    bf16x8 a[2];
    #pragma unroll
    for (int ks = 0; ks < 2; ++ks) {
        const float* cp = condition + (size_t)(r0 + wm * 16 + lm) * 64 + ks * 32 + lg * 8;
        a[ks] = pack8(*(const float4*)cp, *(const float4*)(cp + 4));
    }
    f32x4 acc[24];
    #pragma unroll
    for (int jj = 0; jj < 24; ++jj)
        #pragma unroll
        for (int z = 0; z < 4; ++z) acc[jj][z] = 0.f;

    #pragma unroll
    for (int jj = 0; jj < 24; ++jj) {
        int tile = 2 * jj + wn;
        const u16* bp = cwcbf + (size_t)(tile * 16 + lm) * 64;
        #pragma unroll
        for (int ks = 0; ks < 2; ++ks)
            acc[jj] = MFMA(a[ks], *(const bf16x8*)(bp + ks * 32 + lg * 8), acc[jj]);
    }
    int wv[4];
    #pragma unroll
    for (int j = 0; j < 4; ++j) wv[j] = tok_used[r0 + wm * 16 + lg * 4 + j];
    #pragma unroll
    for (int jj = 0; jj < 24; ++jj) {
        int col = (2 * jj + wn) * 16 + lm;
        #pragma unroll
        for (int j = 0; j < 4; ++j) {
            int g = r0 + wm * 16 + lg * 4 + j;
            float v = acc[jj][j] + bf2f(gic[(size_t)wv[j] * H3 + col]);
            gi_full[(size_t)g * H3 + col] = f2bf(v);
        }
    }
}

// ---------------------------------------------------------------------------
// GRU: 128 blocks x 512 thr, 64 rows/block, 16 steps.
// 16 chunks/step (8 col-groups x 2 K-halves), gate finalized per group with
// only 3 live accumulators. Depth-3 prefetch, exact vmcnt (stores quarantined
// at step end behind wait_vm0).
// ---------------------------------------------------------------------------
__global__ __launch_bounds__(512) void k_gru(
    const u16* __restrict__ whhr_f, const u16* __restrict__ whhr_b,
    const u16* __restrict__ gif, const u16* __restrict__ gib,
    const float* __restrict__ gbhh_f, const float* __restrict__ gbhh_b,
    const u16* __restrict__ w2bf, const float* __restrict__ b2,
    float* __restrict__ Bf, float* __restrict__ Bb,
    const int* __restrict__ lines)
{
    __shared__ __align__(16) u16 hlds[64 * 264];       // 33.8 KB
    __shared__ __align__(16) u16 wbuf_s[4][12288];     // 96 KB (4 x 24KB)
    __shared__ __align__(16) u16 w2l[4096];            // 8 KB
    __shared__ int lns[1024];                          // 4 KB

    const int tid = threadIdx.x, lane = tid & 63, w = tid >> 6;
    const int lm = lane & 15, lg = lane >> 4;
    const int wm = w >> 1, wn = w & 1;
    const int bid = blockIdx.x;
    const int dir = bid >> 6, lb = bid & 63;
    const int ii = lb >> 2, nb = (lb & 3) << 6;
    const u16*   W    = dir ? whhr_b : whhr_f;
    const u16*   git  = dir ? gib : gif;
    const float* bhhs = dir ? gbhh_b : gbhh_f;
    float*       Bout = dir ? Bb : Bf;

    float bn[8];
    #pragma unroll
    for (int cgx = 0; cgx < 8; ++cgx) bn[cgx] = bhhs[512 + cgx * 32 + wn * 16 + lm];
    const float b2e = (lm < 8) ? b2[lm] : 0.f;

    for (int k = tid; k < 64 * 264; k += 512) hlds[k] = 0;
    for (int k = tid; k < 1024; k += 512)
        lns[k] = lines[(nb + (k >> 4)) * NLL + (k & 15)];
    for (int k = tid; k < 4096; k += 512) w2l[k] = w2bf[k];
    __syncthreads();

    bf16x8 a[8];
    #pragma unroll
    for (int ks = 0; ks < 8; ++ks)
        a[ks] = *(const bf16x8*)&hlds[(wm * 16 + lm) * 264 + ks * 32 + lg * 8];

    stage24k(W, wbuf_s[0], 0, w, lane);
    stage24k(W, wbuf_s[1], 1, w, lane);
    stage24k(W, wbuf_s[2], 2, w, lane);

    for (int s = 0; s < 16; ++s) {
        const int jpos = dir ? (15 - s) : s;
        const int jt = (ii + jpos) & 15;
        f32x4 AR, AZ, AN;

#define GRU_GROUP(CG)                                                        \
        ZERO4(AR) ZERO4(AZ) ZERO4(AN)                                        \
        DO_CHUNK(2*(CG),     0, AR, AZ, AN)                                  \
        DO_CHUNK(2*(CG) + 1, 1, AR, AZ, AN)                                  \
        {                                                                    \
            const int col_ = (CG) * 32 + wn * 16 + lm;                       \
            _Pragma("unroll")                                                \
            for (int j = 0; j < 4; ++j) {                                    \
                const int lrow_ = wm * 16 + lg * 4 + j;                      \
                const int tok_ = lns[lrow_ * 16 + jt];                       \
                const u16* gi_ = git + (size_t)tok_ * H3;                    \
                float rg_ = sigm(bf2f(gi_[col_]) + AR[j]);                   \
                float zg_ = sigm(bf2f(gi_[col_ + 256]) + AZ[j]);             \
                float ng_ = tanhfast(bf2f(gi_[col_ + 512])                   \
                                     + rg_ * (AN[j] + bn[CG]));              \
                float ho_ = bf2f(hlds[lrow_ * 264 + col_]);                  \
                hlds[lrow_ * 264 + col_] = f2bf((1.f - zg_) * ng_ + zg_ * ho_); \
            }                                                                \
        }
        GRU_GROUP(0) GRU_GROUP(1) GRU_GROUP(2) GRU_GROUP(3)
        GRU_GROUP(4) GRU_GROUP(5) GRU_GROUP(6) GRU_GROUP(7)
#undef GRU_GROUP

        wait_lgkm0(); bar();                 // h_new visible block-wide

        // reload A-frags (h_new) + fused B projection via MFMA
        #pragma unroll
        for (int ks = 0; ks < 8; ++ks)
            a[ks] = *(const bf16x8*)&hlds[(wm * 16 + lm) * 264 + ks * 32 + lg * 8];
        {
            f32x4 accB; ZERO4(accB)
            #pragma unroll
            for (int ks = 0; ks < 8; ++ks) {
                bf16x8 wf = *(const bf16x8*)&w2l[lm * 256 + ks * 32 + lg * 8];
                accB = MFMA(a[ks], wf, accB);
            }
            if (lm < 8) {
                #pragma unroll
                for (int j = 0; j < 4; ++j) {
                    int nn = nb + wm * 16 + lg * 4 + j;
                    Bout[(((size_t)ii * NN + nn) * NLL + jpos) * NEE + lm] = sigm(accB[j] + b2e);
                }
            }
        }
        wait_vm0();                           // quarantine stores from the ladder
        if (s < 15) {
            stage24k(W, wbuf_s[0], 0, w, lane);
            stage24k(W, wbuf_s[1], 1, w, lane);
            stage24k(W, wbuf_s[2], 2, w, lane);
        }
    }
}

// ---------------------------------------------------------------------------
// Controller: 4 blocks x 512 thr, 64 rows/block, 32 steps. Same pipeline;
// gate inputs from gi_full. Coalesced out/Hallbf store phase from hlds.
// ---------------------------------------------------------------------------
__global__ __launch_bounds__(512) void k_ctrl(
    const u16* __restrict__ cwhr, const u16* __restrict__ gi_full,
    const float* __restrict__ cbhh, const float* __restrict__ h0,
    u16* __restrict__ Hallbf, float* __restrict__ out)
{
    __shared__ __align__(16) u16 hlds[64 * 264];       // 33.8 KB
    __shared__ __align__(16) u16 wbuf_s[4][12288];     // 96 KB

    const int tid = threadIdx.x, lane = tid & 63, w = tid >> 6;
    const int lm = lane & 15, lg = lane >> 4;
    const int wm = w >> 1, wn = w & 1;
    const int cb = blockIdx.x;                         // rows cb*64..+64
    const u16* W = cwhr;

    float bn[8];
    #pragma unroll
    for (int cgx = 0; cgx < 8; ++cgx) bn[cgx] = cbhh[512 + cgx * 32 + wn * 16 + lm];

    {   // h0 -> hlds (bf16)
        int lrow = tid >> 3, c0 = (tid & 7) * 32;
        u16 tmp[32];
        #pragma unroll
        for (int k = 0; k < 32; ++k)
            tmp[k] = f2bf(h0[(size_t)(cb * 64 + lrow) * HH + c0 + k]);
        #pragma unroll
        for (int q = 0; q < 4; ++q)
            *(uint4*)&hlds[lrow * 264 + c0 + q * 8] = *(uint4*)&tmp[q * 8];
    }
    __syncthreads();

    bf16x8 a[8];
    #pragma unroll
    for (int ks = 0; ks < 8; ++ks)
        a[ks] = *(const bf16x8*)&hlds[(wm * 16 + lm) * 264 + ks * 32 + lg * 8];

    stage24k(W, wbuf_s[0], 0, w, lane);
    stage24k(W, wbuf_s[1], 1, w, lane);
    stage24k(W, wbuf_s[2], 2, w, lane);

    for (int s = 0; s < TT; ++s) {
        f32x4 AR, AZ, AN;

#define CTRL_GROUP(CG)                                                       \
        ZERO4(AR) ZERO4(AZ) ZERO4(AN)                                        \
        DO_CHUNK(2*(CG),     0, AR, AZ, AN)                                  \
        DO_CHUNK(2*(CG) + 1, 1, AR, AZ, AN)                                  \
        {                                                                    \
            const int col_ = (CG) * 32 + wn * 16 + lm;                       \
            _Pragma("unroll")                                                \
            for (int j = 0; j < 4; ++j) {                                    \
                const int lrow_ = wm * 16 + lg * 4 + j;                      \
                const u16* gi_ = gi_full                                     \
                    + (size_t)(s * NN + cb * 64 + lrow_) * H3;               \
                float rg_ = sigm(bf2f(gi_[col_]) + AR[j]);                   \
                float zg_ = sigm(bf2f(gi_[col_ + 256]) + AZ[j]);             \
                float ng_ = tanhfast(bf2f(gi_[col_ + 512])                   \
                                     + rg_ * (AN[j] + bn[CG]));              \
                float ho_ = bf2f(hlds[lrow_ * 264 + col_]);                  \
                hlds[lrow_ * 264 + col_] = f2bf((1.f - zg_) * ng_ + zg_ * ho_); \
            }                                                                \
        }
        CTRL_GROUP(0) CTRL_GROUP(1) CTRL_GROUP(2) CTRL_GROUP(3)
        CTRL_GROUP(4) CTRL_GROUP(5) CTRL_GROUP(6) CTRL_GROUP(7)
#undef CTRL_GROUP

        wait_lgkm0(); bar();                  // h_new complete in hlds

        // reload A-frags (h_new)
        #pragma unroll
        for (int ks = 0; ks < 8; ++ks)
            a[ks] = *(const bf16x8*)&hlds[(wm * 16 + lm) * 264 + ks * 32 + lg * 8];

        // coalesced store phase: out (f32) + Hallbf (bf16) from hlds
        {
            int lrow = tid >> 3, c0 = (tid & 7) * 32;
            size_t g = (size_t)s * NN + cb * 64 + lrow;
            #pragma unroll
            for (int q = 0; q < 4; ++q)
                *(uint4*)&Hallbf[g * HH + c0 + q * 8] =
                    *(const uint4*)&hlds[lrow * 264 + c0 + q * 8];
            float* orow = out + g * OW + 4 + c0;
            #pragma unroll
            for (int k = 0; k < 32; ++k)
                orow[k] = bf2f(hlds[lrow * 264 + c0 + k]);
        }
        wait_vm0();                           // quarantine stores
        if (s < TT - 1) {
            stage24k(W, wbuf_s[0], 0, w, lane);
            stage24k(W, wbuf_s[1], 1, w, lane);
            stage24k(W, wbuf_s[2], 2, w, lane);
        }
    }
}

// ---------------------------------------------------------------------------
// Stick-breaking + reversals + roll into final P layout (verified)
// ---------------------------------------------------------------------------
__global__ __launch_bounds__(256) void k_stick(
    const float* __restrict__ Bf, const float* __restrict__ Bb,
    float* __restrict__ P_final)
{
    int idx = blockIdx.x * 256 + threadIdx.x;
    if (idx >= 16 * 256 * 8) return;
    int e = idx & 7, n = (idx >> 3) & 255, i = idx >> 11;
    const float* bf = Bf + ((size_t)(i * NN + n) * NLL) * NEE + e;
    const float* bb = Bb + ((size_t)(i * NN + n) * NLL) * NEE + e;
    int i2 = (i + 15) & 15;
    float* dst = P_final + ((size_t)(i2 * NN + n) * 32) * NEE + e;
    float cum = 1.f;
    #pragma unroll
    for (int m = 0; m < 16; ++m) {
        float c0 = bf[m * NEE];
        float c1 = bb[(15 - m) * NEE];
        float v0 = c0 * cum;
        cum *= (1.f - c0);
        float v1 = (m < 15) ? c1 * cum : cum;
        cum *= (1.f - c1);
        dst[(size_t)(((17 + m) & 31)) * NEE] = v0;
        dst[(size_t)((16 - m)) * NEE]        = v1;
    }
}

// ---------------------------------------------------------------------------
// Batched MLP layer: Out = bf16(relu(A @ W^T + bias)), A (8192,256) bf16
// ---------------------------------------------------------------------------
__global__ __launch_bounds__(256) void k_mlp(
    const u16* __restrict__ A, const u16* __restrict__ W,
    const float* __restrict__ bias, u16* __restrict__ Out)
{
    __shared__ u16 ot[32 * 264];
    const int g0 = blockIdx.x * 32;
    const int tid = threadIdx.x, lane = tid & 63, w = tid >> 6;
    const int lm = lane & 15, lg = lane >> 4;
    f32x4 acc[4][2];
    #pragma unroll
    for (int c = 0; c < 4; ++c)
        #pragma unroll
        for (int r = 0; r < 2; ++r)
            #pragma unroll
            for (int z = 0; z < 4; ++z) acc[c][r][z] = 0.f;
    #pragma unroll
    for (int ks = 0; ks < 8; ++ks) {
        bf16x8 a0 = *(const bf16x8*)&A[(size_t)(g0 + lm) * 256 + ks * 32 + lg * 8];
        bf16x8 a1 = *(const bf16x8*)&A[(size_t)(g0 + 16 + lm) * 256 + ks * 32 + lg * 8];
        #pragma unroll
        for (int cf = 0; cf < 4; ++cf) {
            const u16* bp = W + (size_t)(w * 64 + cf * 16 + lm) * 256 + ks * 32 + lg * 8;
            bf16x8 b = *(const bf16x8*)bp;
            acc[cf][0] = MFMA(a0, b, acc[cf][0]);
            acc[cf][1] = MFMA(a1, b, acc[cf][1]);
        }
    }
    #pragma unroll
    for (int cf = 0; cf < 4; ++cf) {
        int col = w * 64 + cf * 16 + lm;
        float bs = bias[col];
        #pragma unroll
        for (int rf = 0; rf < 2; ++rf)
            #pragma unroll
            for (int j = 0; j < 4; ++j) {
                int lrow = rf * 16 + lg * 4 + j;
                ot[lrow * 264 + col] = f2bf(fmaxf(acc[cf][rf][j] + bs, 0.f));
            }
    }
    __syncthreads();
    int lrow = tid >> 3, c0 = (tid & 7) * 32;
    const uint4* src = (const uint4*)&ot[lrow * 264 + c0];
    uint4* dst = (uint4*)&Out[(size_t)(g0 + lrow) * 256 + c0];
    dst[0] = src[0]; dst[1] = src[1]; dst[2] = src[2]; dst[3] = src[3];
}

// ---------------------------------------------------------------------------
// Heads: 25 logits per row + softmaxes + v + p_probs
// ---------------------------------------------------------------------------
__global__ __launch_bounds__(256) void k_heads(
    const u16* __restrict__ zbf,
    const float* __restrict__ aw, const float* __restrict__ ab,
    const float* __restrict__ ow, const float* __restrict__ ob,
    const float* __restrict__ cw, const float* __restrict__ cb,
    const float* __restrict__ P_final, const int* __restrict__ w_used,
    float* __restrict__ out)
{
    __shared__ float zt[32 * 258];
    __shared__ float hd[32][28];
    __shared__ float o8[32][8];
    __shared__ int   wv[32];
    const int g0 = blockIdx.x * 32, tid = threadIdx.x;
    {
        int lrow = tid >> 3, c0 = (tid & 7) * 32;
        const u16* src = &zbf[(size_t)(g0 + lrow) * 256 + c0];
        #pragma unroll
        for (int k = 0; k < 32; ++k) zt[lrow * 258 + c0 + k] = bf2f(src[k]);
    }
    if (tid < 32) wv[tid] = w_used[g0 + tid];
    __syncthreads();
    {
        int r = tid >> 3, s = tid & 7;
        const float* z = &zt[r * 258];
        float a1 = ab[s], a2 = ab[8 + s], a3 = ob[s], a4 = cb[0];
        const float* w1 = aw + s * 256;
        const float* w2_ = aw + (8 + s) * 256;
        const float* w3 = ow + s * 256;
        for (int c = 0; c < 256; ++c) {
            float zv = z[c];
            a1 += zv * w1[c]; a2 += zv * w2_[c]; a3 += zv * w3[c]; a4 += zv * cw[c];
        }
        hd[r][s] = a1; hd[r][8 + s] = a2; hd[r][16 + s] = a3;
        if (s == 0) hd[r][24] = a4;
    }
    __syncthreads();
    if (tid < 32) {
        int r = tid; int g = g0 + r;
        float* orow = out + (size_t)g * OW;
        float mx = hd[r][0];
        #pragma unroll
        for (int k = 1; k < 16; ++k) mx = fmaxf(mx, hd[r][k]);
        float ex[16], ssum = 0.f;
        #pragma unroll
        for (int k = 0; k < 16; ++k) { ex[k] = __expf(hd[r][k] - mx); ssum += ex[k]; }
        float inv = 1.f / ssum;
        #pragma unroll
        for (int k = 0; k < 16; ++k) orow[260 + k] = ex[k] * inv;
        orow[3] = hd[r][24];
        float mo = hd[r][16];
        #pragma unroll
        for (int k = 1; k < 8; ++k) mo = fmaxf(mo, hd[r][16 + k]);
        float eo[8], so = 0.f;
        #pragma unroll
        for (int k = 0; k < 8; ++k) { eo[k] = __expf(hd[r][16 + k] - mo); so += eo[k]; }
        float invo = 1.f / so;
        #pragma unroll
        for (int k = 0; k < 8; ++k) o8[r][k] = eo[k] * invo;
    }
    __syncthreads();
    {
        int r = tid >> 3, kb = tid & 7;
        int g = g0 + r, n = g & 255;
        const float* base = P_final + ((size_t)(wv[r] * NN + n) * 32) * NEE;
        float* orow = out + (size_t)g * OW + 276;
        #pragma unroll
        for (int m = 0; m < 4; ++m) {
            int k = kb + m * 8;
            const float* pe = base + k * NEE;
            float a = 0.f;
            #pragma unroll
            for (int e = 0; e < 8; ++e) a += pe[e] * o8[r][e];
            orow[k] = a;
        }
    }
}

// ---------------------------------------------------------------------------
extern "C" void kernel_launch(void* const* d_in, const int* in_sizes, int n_in,
                              void* d_out, int out_size, void* d_ws, size_t ws_size,
                              hipStream_t stream) {
    const float* condition = (const float*)d_in[0];
    const int*   lines     = (const int*)  d_in[1];
    const int*   actions   = (const int*)  d_in[2];
    const float* h0        = (const float*)d_in[3];
    const int*   w0        = (const int*)  d_in[4];
    const float* embed     = (const float*)d_in[5];
    const float* gwih_f    = (const float*)d_in[6];
    const float* gwhh_f    = (const float*)d_in[7];
    const float* gbih_f    = (const float*)d_in[8];
    const float* gbhh_f    = (const float*)d_in[9];
    const float* gwih_b    = (const float*)d_in[10];
    const float* gwhh_b    = (const float*)d_in[11];
    const float* gbih_b    = (const float*)d_in[12];
    const float* gbhh_b    = (const float*)d_in[13];
    const float* w2        = (const float*)d_in[14];
    const float* b2        = (const float*)d_in[15];
    const float* cwih      = (const float*)d_in[16];
    const float* cwhh      = (const float*)d_in[17];
    const float* cbih      = (const float*)d_in[18];
    const float* cbhh      = (const float*)d_in[19];
    const float* mw1       = (const float*)d_in[20];
    const float* mb1       = (const float*)d_in[21];
    const float* mw2       = (const float*)d_in[22];
    const float* mb2       = (const float*)d_in[23];
    const float* ow        = (const float*)d_in[24];
    const float* ob        = (const float*)d_in[25];
    const float* aw        = (const float*)d_in[26];
    const float* ab        = (const float*)d_in[27];
    const float* cw        = (const float*)d_in[28];
    const float* cb        = (const float*)d_in[29];
    float* out = (float*)d_out;

    // workspace carve-up (~23 MB, aliased)
    char* base = (char*)d_ws;
    auto alloc = [&](size_t bytes) { char* r = base; base += (bytes + 255) & ~(size_t)255; return r; };
    u16*   gif_tok = (u16*)alloc(64 * H3 * 2);
    u16*   gib_tok = (u16*)alloc(64 * H3 * 2);
    u16*   gic_tok = (u16*)alloc(64 * H3 * 2);
    u16*   whhr_f  = (u16*)alloc(H3 * 256 * 2);
    u16*   whhr_b  = (u16*)alloc(H3 * 256 * 2);
    u16*   cwhr    = (u16*)alloc(H3 * 256 * 2);
    u16*   mw1bf   = (u16*)alloc(256 * 256 * 2);
    u16*   mw2bf   = (u16*)alloc(256 * 256 * 2);
    u16*   w2bf    = (u16*)alloc(16 * 256 * 2);
    u16*   cwcbf   = (u16*)alloc(H3 * 64 * 2);
    u16*   gi_full = (u16*)alloc((size_t)TT * NN * H3 * 2);   // 12.6 MB
    float* Bf      = (float*)alloc((size_t)16 * 256 * 16 * 8 * 4);
    float* Bb      = (float*)alloc((size_t)16 * 256 * 16 * 8 * 4);
    u16*   Hallbf  = (u16*)alloc((size_t)TT * NN * 256 * 2);
    int*   w_used  = (int*)alloc((size_t)TT * NN * 4);
    int*   tok_used= (int*)alloc((size_t)TT * NN * 4);
    // aliases (dead-after-ctrl / dead-after-stick regions)
    float* P_final = (float*)gi_full;                          // written post-ctrl
    u16*   zbf     = (u16*)((char*)gi_full + (size_t)4 * 1024 * 1024);
    u16*   z1bf    = (u16*)Bf;                                 // after k_stick

    k_prep<<<3024, 256, 0, stream>>>(gwhh_f, gwhh_b, cwhh, mw1, mw2, w2, cwih,
                                     whhr_f, whhr_b, cwhr, mw1bf, mw2bf, w2bf, cwcbf);

    k_tok<<<18, 256, 0, stream>>>(embed,
                                  gwih_f, gbih_f, gbhh_f,
                                  gwih_b, gbih_b, gbhh_b,
                                  cwih, cbih, cbhh,
                                  gif_tok, gib_tok, gic_tok);

    k_wtraj<<<1, 256, 0, stream>>>(actions, w0, lines, out, w_used, tok_used);

    k_cg<<<256, 256, 0, stream>>>(condition, cwcbf, gic_tok, tok_used, gi_full);

    k_gru<<<128, 512, 0, stream>>>(whhr_f, whhr_b, gif_tok, gib_tok, gbhh_f, gbhh_b,
                                   w2bf, b2, Bf, Bb, lines);

    k_ctrl<<<4, 512, 0, stream>>>(cwhr, gi_full, cbhh, h0, Hallbf, out);

    k_stick<<<128, 256, 0, stream>>>(Bf, Bb, P_final);

    k_mlp<<<256, 256, 0, stream>>>(Hallbf, mw1bf, mb1, z1bf);
    k_mlp<<<256, 256, 0, stream>>>(z1bf, mw2bf, mb2, zbf);

    k_heads<<<256, 256, 0, stream>>>(zbf, aw, ab, ow, ob, cw, cb, P_final, w_used, out);
}

// Round 10
// 979.303 us; speedup vs baseline: 1.7976x; 1.0013x over previous
//
#include <hip/hip_runtime.h>
#include <cstddef>
#include <cstdint>

#define TT   32
#define NN   256
#define NLL  16
#define HH   256
#define CONDD 64
#define NEE  8
#define H3   768
#define OW   308

typedef __attribute__((ext_vector_type(8))) short bf16x8;
typedef __attribute__((ext_vector_type(4))) float f32x4;
typedef unsigned short u16;

__device__ __forceinline__ float sigm(float x)     { return 1.f / (1.f + __expf(-x)); }
__device__ __forceinline__ float tanhfast(float x) { return 1.f - 2.f / (__expf(2.f * x) + 1.f); }
__device__ __forceinline__ float bf2f(u16 h) {
    union { unsigned u; float f; } v; v.u = ((unsigned)h) << 16; return v.f;
}
__device__ __forceinline__ u16 f2bf(float f) {   // round-to-nearest-even
    union { float f; unsigned u; } v; v.f = f;
    unsigned r = v.u + 0x7fffu + ((v.u >> 16) & 1u);
    return (u16)(r >> 16);
}
__device__ __forceinline__ bf16x8 pack8(float4 f0, float4 f1) {
    union { u16 u[8]; bf16x8 v; } r;
    r.u[0] = f2bf(f0.x); r.u[1] = f2bf(f0.y); r.u[2] = f2bf(f0.z); r.u[3] = f2bf(f0.w);
    r.u[4] = f2bf(f1.x); r.u[5] = f2bf(f1.y); r.u[6] = f2bf(f1.z); r.u[7] = f2bf(f1.w);
    return r.v;
}
#define MFMA(a, b, c) __builtin_amdgcn_mfma_f32_16x16x32_bf16(a, b, c, 0, 0, 0)

// ---- async global->LDS staging --------------------------------------------
__device__ __forceinline__ void gl_lds16(const u16* g, u16* l) {
    __builtin_amdgcn_global_load_lds(
        (const __attribute__((address_space(1))) unsigned int*)(const void*)g,
        (__attribute__((address_space(3))) unsigned int*)(void*)l, 16, 0, 0);
}
// Stage one 24KB chunk (96 rows x 128 K-entries bf16) of the gate-triple
// reordered weight matrix Wr. LDS dest linear; SOURCE 16B-granule pre-swizzled
// (p ^ (q&15)) so the swizzled ds_read_b128 on the consumer side is uniform
// across banks (source perm == read perm, involution). 3 instrs per wave.
__device__ __forceinline__ void stage24k(const u16* __restrict__ Wr, u16* buf,
                                         int c, int w, int lane) {
#pragma unroll
    for (int r = 0; r < 3; ++r) {
        int G = (w * 3 + r) * 64 + lane;   // granule 0..1535
        int q = G >> 4, p = G & 15;        // row-in-chunk, granule-in-row
        const u16* src = Wr + ((size_t)(c * 96 + q) << 7) + ((p ^ (q & 15)) << 3);
        gl_lds16(src, buf + ((w * 3 + r) << 9));   // wave-uniform LDS base
    }
}
__device__ __forceinline__ void wait_vm9()   { asm volatile("s_waitcnt vmcnt(9)" ::: "memory"); }
__device__ __forceinline__ void wait_vm6()   { asm volatile("s_waitcnt vmcnt(6)" ::: "memory"); }
__device__ __forceinline__ void wait_vm3()   { asm volatile("s_waitcnt vmcnt(3)" ::: "memory"); }
__device__ __forceinline__ void wait_vm0()   { asm volatile("s_waitcnt vmcnt(0)" ::: "memory"); }
__device__ __forceinline__ void wait_lgkm0() { asm volatile("s_waitcnt lgkmcnt(0)" ::: "memory"); }
__device__ __forceinline__ void bar() {
    asm volatile("" ::: "memory");
    __builtin_amdgcn_s_barrier();
    asm volatile("" ::: "memory");
}

#define ZERO4(X) { X[0] = 0.f; X[1] = 0.f; X[2] = 0.f; X[3] = 0.f; }

// One pipelined chunk: stage chunk C+3 (if within step), counted wait, bar,
// 12 MFMAs (r,z,n tiles for this wave's 16-col slice, K-half KH), bar.
// In scope: W, wbuf_s, w, lane, wn, lm, lg, a[8].
#define DO_CHUNK(C, KH, AR, AZ, AN)                                          \
  {                                                                          \
    if ((C) <= 12) { stage24k(W, wbuf_s[((C)+3)&3], (C)+3, w, lane); wait_vm9(); } \
    else if ((C) == 13) { wait_vm6(); }                                      \
    else if ((C) == 14) { wait_vm3(); }                                      \
    else { wait_vm0(); }                                                     \
    bar();                                                                   \
    {                                                                        \
      const u16* wb_ = wbuf_s[(C)&3];                                        \
      const int rb_ = wn * 16 + lm;                                          \
      _Pragma("unroll")                                                      \
      for (int k2 = 0; k2 < 4; ++k2) {                                       \
        const int go_ = (((k2 * 4 + lg) ^ lm) << 3);                         \
        AR = MFMA(a[(KH)*4 + k2], *(const bf16x8*)&wb_[(rb_) * 128 + go_], AR); \
        AZ = MFMA(a[(KH)*4 + k2], *(const bf16x8*)&wb_[(32 + rb_) * 128 + go_], AZ); \
        AN = MFMA(a[(KH)*4 + k2], *(const bf16x8*)&wb_[(64 + rb_) * 128 + go_], AN); \
      }                                                                      \
    }                                                                        \
    bar();                                                                   \
  }

// ---------------------------------------------------------------------------
// fp32 -> bf16 weight casts; whh/cwhh go through the gate-triple chunk remap:
// Wr[(c*96+q)*128 + k], c=cg*2+kh, q=g*32+cj  <-  W[(g*256+cg*32+cj)*256+kh*128+k]
// ---------------------------------------------------------------------------
__device__ __forceinline__ long wremap(long i) {
    long k = i & 127, row = i >> 7;
    long c = row / 96, q = row % 96;
    long cg = c >> 1, kh = c & 1;
    long g = q >> 5, cj = q & 31;
    return (g * 256 + cg * 32 + cj) * 256 + kh * 128 + k;
}
__global__ __launch_bounds__(256) void k_prep(
    const float* __restrict__ gwhh_f, const float* __restrict__ gwhh_b,
    const float* __restrict__ cwhh,  const float* __restrict__ mw1,
    const float* __restrict__ mw2,   const float* __restrict__ w2,
    const float* __restrict__ cwih,
    u16* __restrict__ whhr_f, u16* __restrict__ whhr_b, u16* __restrict__ cwhr,
    u16* __restrict__ mw1bf, u16* __restrict__ mw2bf, u16* __restrict__ w2bf,
    u16* __restrict__ cwcbf)
{
    long i = (long)blockIdx.x * 256 + threadIdx.x;
    if (i < 196608) { whhr_f[i] = f2bf(gwhh_f[wremap(i)]); return; } i -= 196608;
    if (i < 196608) { whhr_b[i] = f2bf(gwhh_b[wremap(i)]); return; } i -= 196608;
    if (i < 196608) { cwhr[i]   = f2bf(cwhh[wremap(i)]);   return; } i -= 196608;
    if (i < 65536)  { mw1bf[i]  = f2bf(mw1[i]);   return; } i -= 65536;
    if (i < 65536)  { mw2bf[i]  = f2bf(mw2[i]);   return; } i -= 65536;
    if (i < 4096)   { long r = i >> 8, c = i & 255;
                      w2bf[i] = (r < 8) ? f2bf(w2[r * 256 + c]) : (u16)0; return; } i -= 4096;
    if (i < 49152)  { long r = i >> 6, c = i & 63; cwcbf[i] = f2bf(cwih[r * 320 + c]); }
}

// ---------------------------------------------------------------------------
// Per-token gi tables via MFMA (biases folded; gbhh/cbhh r,z parts folded too)
// ---------------------------------------------------------------------------
__global__ __launch_bounds__(256) void k_tok(
    const float* __restrict__ embed,
    const float* __restrict__ gwih_f, const float* __restrict__ gbih_f, const float* __restrict__ gbhh_f,
    const float* __restrict__ gwih_b, const float* __restrict__ gbih_b, const float* __restrict__ gbhh_b,
    const float* __restrict__ cwih,   const float* __restrict__ cbih,   const float* __restrict__ cbhh,
    u16* __restrict__ gif, u16* __restrict__ gib, u16* __restrict__ gic)
{
    const int mat = blockIdx.x / 6, ch = blockIdx.x % 6;
    const int tid = threadIdx.x, lane = tid & 63, w = tid >> 6;
    const int lm = lane & 15, lg = lane >> 4;
    const float *W, *b1, *b2v; int wstride, woff; u16* dst;
    if (mat == 0)      { W = gwih_f; b1 = gbih_f; b2v = gbhh_f; wstride = 256; woff = 0;  dst = gif; }
    else if (mat == 1) { W = gwih_b; b1 = gbih_b; b2v = gbhh_b; wstride = 256; woff = 0;  dst = gib; }
    else               { W = cwih;   b1 = cbih;   b2v = cbhh;   wstride = 320; woff = 64; dst = gic; }

    bf16x8 a[8];
    #pragma unroll
    for (int ks = 0; ks < 8; ++ks) {
        const float* ep = embed + (size_t)(w * 16 + lm) * 256 + ks * 32 + lg * 8;
        a[ks] = pack8(*(const float4*)ep, *(const float4*)(ep + 4));
    }
    f32x4 acc[8];
    #pragma unroll
    for (int nt = 0; nt < 8; ++nt)
        #pragma unroll
        for (int z = 0; z < 4; ++z) acc[nt][z] = 0.f;

    #pragma unroll
    for (int nt = 0; nt < 8; ++nt) {
        int col = ch * 128 + nt * 16 + lm;
        const float* wp = W + (size_t)col * wstride + woff;
        #pragma unroll
        for (int ks = 0; ks < 8; ++ks) {
            bf16x8 b = pack8(*(const float4*)(wp + ks * 32 + lg * 8),
                             *(const float4*)(wp + ks * 32 + lg * 8 + 4));
            acc[nt] = MFMA(a[ks], b, acc[nt]);
        }
    }
    #pragma unroll
    for (int nt = 0; nt < 8; ++nt) {
        int col = ch * 128 + nt * 16 + lm;
        float bias = b1[col] + (col < 512 ? b2v[col] : 0.f);
        #pragma unroll
        for (int j = 0; j < 4; ++j) {
            int v = w * 16 + lg * 4 + j;
            dst[(size_t)v * H3 + col] = f2bf(acc[nt][j] + bias);
        }
    }
}

// ---------------------------------------------------------------------------
// w-trajectory + out[.,.,0..2] + tok_used
// ---------------------------------------------------------------------------
__global__ void k_wtraj(const int* __restrict__ actions, const int* __restrict__ w0,
                        const int* __restrict__ lines,
                        float* __restrict__ out, int* __restrict__ w_used,
                        int* __restrict__ tok_used)
{
    int n = threadIdx.x;
    int w = w0[n];
    for (int t = 0; t < TT; ++t) {
        int A = actions[((size_t)t * NN + n) * 2 + 0];
        int W = actions[((size_t)t * NN + n) * 2 + 1];
        w_used[t * NN + n] = w;
        tok_used[t * NN + n] = lines[n * NLL + w];
        int wn = w + W - NLL;
        wn = wn < 0 ? 0 : (wn > NLL - 1 ? NLL - 1 : wn);
        float* o = out + ((size_t)t * NN + n) * OW;
        o[0] = (float)A; o[1] = (float)W; o[2] = (float)wn;
        w = wn;
    }
}

// ---------------------------------------------------------------------------
// gi_full[t*256+n][col] = bf16( cond[t,n] @ cwc^T[col] + gic[tok_used[t,n]][col] )
// ---------------------------------------------------------------------------
__global__ __launch_bounds__(256) void k_cg(
    const float* __restrict__ condition, const u16* __restrict__ cwcbf,
    const u16* __restrict__ gic, const int* __restrict__ tok_used,
    u16* __restrict__ gi_full)
{
    const int r0 = blockIdx.x * 32;
    const int tid = threadIdx.x, lane = tid & 63, w = tid >> 6;
    const int wm = w >> 1, wn = w & 1;
    const int lm = lane & 15, lg = lane >> 4;

    bf16x8 a[2];
    #pragma unroll
    for (int ks = 0; ks < 2; ++ks) {
        const float* cp = condition + (size_t)(r0 + wm * 16 + lm) * 64 + ks * 32 + lg * 8;
        a[ks] = pack8(*(const float4*)cp, *(const float4*)(cp + 4));
    }
    f32x4 acc[24];
    #pragma unroll
    for (int jj = 0; jj < 24; ++jj)
        #pragma unroll
        for (int z = 0; z < 4; ++z) acc[jj][z] = 0.f;

    #pragma unroll
    for (int jj = 0; jj < 24; ++jj) {
        int tile = 2 * jj + wn;
        const u16* bp = cwcbf + (size_t)(tile * 16 + lm) * 64;
        #pragma unroll
        for (int ks = 0; ks < 2; ++ks)
            acc[jj] = MFMA(a[ks], *(const bf16x8*)(bp + ks * 32 + lg * 8), acc[jj]);
    }
    int wv[4];
    #pragma unroll
    for (int j = 0; j < 4; ++j) wv[j] = tok_used[r0 + wm * 16 + lg * 4 + j];
    #pragma unroll
    for (int jj = 0; jj < 24; ++jj) {
        int col = (2 * jj + wn) * 16 + lm;
        #pragma unroll
        for (int j = 0; j < 4; ++j) {
            int g = r0 + wm * 16 + lg * 4 + j;
            float v = acc[jj][j] + bf2f(gic[(size_t)wv[j] * H3 + col]);
            gi_full[(size_t)g * H3 + col] = f2bf(v);
        }
    }
}

// ---------------------------------------------------------------------------
// GRU: 128 blocks x 512 thr, 64 rows/block, 16 steps.
// 16 chunks/step (8 col-groups x 2 K-halves), gate finalized per group with
// only 3 live accumulators. Depth-3 prefetch, exact vmcnt (stores quarantined
// at step end behind wait_vm0).
// ---------------------------------------------------------------------------
__global__ __launch_bounds__(512) void k_gru(
    const u16* __restrict__ whhr_f, const u16* __restrict__ whhr_b,
    const u16* __restrict__ gif, const u16* __restrict__ gib,
    const float* __restrict__ gbhh_f, const float* __restrict__ gbhh_b,
    const u16* __restrict__ w2bf, const float* __restrict__ b2,
    float* __restrict__ Bf, float* __restrict__ Bb,
    const int* __restrict__ lines)
{
    __shared__ __align__(16) u16 hlds[64 * 264];       // 33.8 KB
    __shared__ __align__(16) u16 wbuf_s[4][12288];     // 96 KB (4 x 24KB)
    __shared__ __align__(16) u16 w2l[4096];            // 8 KB
    __shared__ int lns[1024];                          // 4 KB

    const int tid = threadIdx.x, lane = tid & 63, w = tid >> 6;
    const int lm = lane & 15, lg = lane >> 4;
    const int wm = w >> 1, wn = w & 1;
    const int bid = blockIdx.x;
    const int dir = bid >> 6, lb = bid & 63;
    const int ii = lb >> 2, nb = (lb & 3) << 6;
    const u16*   W    = dir ? whhr_b : whhr_f;
    const u16*   git  = dir ? gib : gif;
    const float* bhhs = dir ? gbhh_b : gbhh_f;
    float*       Bout = dir ? Bb : Bf;

    float bn[8];
    #pragma unroll
    for (int cgx = 0; cgx < 8; ++cgx) bn[cgx] = bhhs[512 + cgx * 32 + wn * 16 + lm];
    const float b2e = (lm < 8) ? b2[lm] : 0.f;

    for (int k = tid; k < 64 * 264; k += 512) hlds[k] = 0;
    for (int k = tid; k < 1024; k += 512)
        lns[k] = lines[(nb + (k >> 4)) * NLL + (k & 15)];
    for (int k = tid; k < 4096; k += 512) w2l[k] = w2bf[k];
    __syncthreads();

    bf16x8 a[8];
    #pragma unroll
    for (int ks = 0; ks < 8; ++ks)
        a[ks] = *(const bf16x8*)&hlds[(wm * 16 + lm) * 264 + ks * 32 + lg * 8];

    stage24k(W, wbuf_s[0], 0, w, lane);
    stage24k(W, wbuf_s[1], 1, w, lane);
    stage24k(W, wbuf_s[2], 2, w, lane);

    for (int s = 0; s < 16; ++s) {
        const int jpos = dir ? (15 - s) : s;
        const int jt = (ii + jpos) & 15;
        f32x4 AR, AZ, AN;

#define GRU_GROUP(CG)                                                        \
        ZERO4(AR) ZERO4(AZ) ZERO4(AN)                                        \
        DO_CHUNK(2*(CG),     0, AR, AZ, AN)                                  \
        DO_CHUNK(2*(CG) + 1, 1, AR, AZ, AN)                                  \
        {                                                                    \
            const int col_ = (CG) * 32 + wn * 16 + lm;                       \
            _Pragma("unroll")                                                \
            for (int j = 0; j < 4; ++j) {                                    \
                const int lrow_ = wm * 16 + lg * 4 + j;                      \
                const int tok_ = lns[lrow_ * 16 + jt];                       \
                const u16* gi_ = git + (size_t)tok_ * H3;                    \
                float rg_ = sigm(bf2f(gi_[col_]) + AR[j]);                   \
                float zg_ = sigm(bf2f(gi_[col_ + 256]) + AZ[j]);             \
                float ng_ = tanhfast(bf2f(gi_[col_ + 512])                   \
                                     + rg_ * (AN[j] + bn[CG]));              \
                float ho_ = bf2f(hlds[lrow_ * 264 + col_]);                  \
                hlds[lrow_ * 264 + col_] = f2bf((1.f - zg_) * ng_ + zg_ * ho_); \
            }                                                                \
        }
        GRU_GROUP(0) GRU_GROUP(1) GRU_GROUP(2) GRU_GROUP(3)
        GRU_GROUP(4) GRU_GROUP(5) GRU_GROUP(6) GRU_GROUP(7)
#undef GRU_GROUP

        wait_lgkm0(); bar();                 // h_new visible block-wide

        // reload A-frags (h_new) + fused B projection via MFMA
        #pragma unroll
        for (int ks = 0; ks < 8; ++ks)
            a[ks] = *(const bf16x8*)&hlds[(wm * 16 + lm) * 264 + ks * 32 + lg * 8];
        {
            f32x4 accB; ZERO4(accB)
            #pragma unroll
            for (int ks = 0; ks < 8; ++ks) {
                bf16x8 wf = *(const bf16x8*)&w2l[lm * 256 + ks * 32 + lg * 8];
                accB = MFMA(a[ks], wf, accB);
            }
            if (lm < 8) {
                #pragma unroll
                for (int j = 0; j < 4; ++j) {
                    int nn = nb + wm * 16 + lg * 4 + j;
                    Bout[(((size_t)ii * NN + nn) * NLL + jpos) * NEE + lm] = sigm(accB[j] + b2e);
                }
            }
        }
        wait_vm0();                           // quarantine stores from the ladder
        if (s < 15) {
            stage24k(W, wbuf_s[0], 0, w, lane);
            stage24k(W, wbuf_s[1], 1, w, lane);
            stage24k(W, wbuf_s[2], 2, w, lane);
        }
    }
}

// ---------------------------------------------------------------------------
// Controller: 4 blocks x 512 thr, 64 rows/block, 32 steps. Same pipeline;
// gate inputs from gi_full. Coalesced out/Hallbf store phase from hlds.
// ---------------------------------------------------------------------------
__global__ __launch_bounds__(512) void k_ctrl(
    const u16* __restrict__ cwhr, const u16* __restrict__ gi_full,
    const float* __restrict__ cbhh, const float* __restrict__ h0,
    u16* __restrict__ Hallbf, float* __restrict__ out)
{
    __shared__ __align__(16) u16 hlds[64 * 264];       // 33.8 KB
    __shared__ __align__(16) u16 wbuf_s[4][12288];     // 96 KB

    const int tid = threadIdx.x, lane = tid & 63, w = tid >> 6;
    const int lm = lane & 15, lg = lane >> 4;
    const int wm = w >> 1, wn = w & 1;
    const int cb = blockIdx.x;                         // rows cb*64..+64
    const u16* W = cwhr;

    float bn[8];
    #pragma unroll
    for (int cgx = 0; cgx < 8; ++cgx) bn[cgx] = cbhh[512 + cgx * 32 + wn * 16 + lm];

    {   // h0 -> hlds (bf16)
        int lrow = tid >> 3, c0 = (tid & 7) * 32;
        u16 tmp[32];
        #pragma unroll
        for (int k = 0; k < 32; ++k)
            tmp[k] = f2bf(h0[(size_t)(cb * 64 + lrow) * HH + c0 + k]);
        #pragma unroll
        for (int q = 0; q < 4; ++q)
            *(uint4*)&hlds[lrow * 264 + c0 + q * 8] = *(uint4*)&tmp[q * 8];
    }
    __syncthreads();

    bf16x8 a[8];
    #pragma unroll
    for (int ks = 0; ks < 8; ++ks)
        a[ks] = *(const bf16x8*)&hlds[(wm * 16 + lm) * 264 + ks * 32 + lg * 8];

    stage24k(W, wbuf_s[0], 0, w, lane);
    stage24k(W, wbuf_s[1], 1, w, lane);
    stage24k(W, wbuf_s[2], 2, w, lane);

    for (int s = 0; s < TT; ++s) {
        f32x4 AR, AZ, AN;

#define CTRL_GROUP(CG)                                                       \
        ZERO4(AR) ZERO4(AZ) ZERO4(AN)                                        \
        DO_CHUNK(2*(CG),     0, AR, AZ, AN)                                  \
        DO_CHUNK(2*(CG) + 1, 1, AR, AZ, AN)                                  \
        {                                                                    \
            const int col_ = (CG) * 32 + wn * 16 + lm;                       \
            _Pragma("unroll")                                                \
            for (int j = 0; j < 4; ++j) {                                    \
                const int lrow_ = wm * 16 + lg * 4 + j;                      \
                const u16* gi_ = gi_full                                     \
                    + (size_t)(s * NN + cb * 64 + lrow_) * H3;               \
                float rg_ = sigm(bf2f(gi_[col_]) + AR[j]);                   \
                float zg_ = sigm(bf2f(gi_[col_ + 256]) + AZ[j]);             \
                float ng_ = tanhfast(bf2f(gi_[col_ + 512])                   \
                                     + rg_ * (AN[j] + bn[CG]));              \
                float ho_ = bf2f(hlds[lrow_ * 264 + col_]);                  \
                hlds[lrow_ * 264 + col_] = f2bf((1.f - zg_) * ng_ + zg_ * ho_); \
            }                                                                \
        }
        CTRL_GROUP(0) CTRL_GROUP(1) CTRL_GROUP(2) CTRL_GROUP(3)
        CTRL_GROUP(4) CTRL_GROUP(5) CTRL_GROUP(6) CTRL_GROUP(7)
#undef CTRL_GROUP

        wait_lgkm0(); bar();                  // h_new complete in hlds

        // reload A-frags (h_new)
        #pragma unroll
        for (int ks = 0; ks < 8; ++ks)
            a[ks] = *(const bf16x8*)&hlds[(wm * 16 + lm) * 264 + ks * 32 + lg * 8];

        // coalesced store phase: out (f32) + Hallbf (bf16) from hlds
        {
            int lrow = tid >> 3, c0 = (tid & 7) * 32;
            size_t g = (size_t)s * NN + cb * 64 + lrow;
            #pragma unroll
            for (int q = 0; q < 4; ++q)
                *(uint4*)&Hallbf[g * HH + c0 + q * 8] =
                    *(const uint4*)&hlds[lrow * 264 + c0 + q * 8];
            float* orow = out + g * OW + 4 + c0;
            #pragma unroll
            for (int k = 0; k < 32; ++k)
                orow[k] = bf2f(hlds[lrow * 264 + c0 + k]);
        }
        wait_vm0();                           // quarantine stores
        if (s < TT - 1) {
            stage24k(W, wbuf_s[0], 0, w, lane);
            stage24k(W, wbuf_s[1], 1, w, lane);
            stage24k(W, wbuf_s[2], 2, w, lane);
        }
    }
}

// ---------------------------------------------------------------------------
// Stick-breaking + reversals + roll into final P layout (verified)
// ---------------------------------------------------------------------------
__global__ __launch_bounds__(256) void k_stick(
    const float* __restrict__ Bf, const float* __restrict__ Bb,
    float* __restrict__ P_final)
{
    int idx = blockIdx.x * 256 + threadIdx.x;
    if (idx >= 16 * 256 * 8) return;
    int e = idx & 7, n = (idx >> 3) & 255, i = idx >> 11;
    const float* bf = Bf + ((size_t)(i * NN + n) * NLL) * NEE + e;
    const float* bb = Bb + ((size_t)(i * NN + n) * NLL) * NEE + e;
    int i2 = (i + 15) & 15;
    float* dst = P_final + ((size_t)(i2 * NN + n) * 32) * NEE + e;
    float cum = 1.f;
    #pragma unroll
    for (int m = 0; m < 16; ++m) {
        float c0 = bf[m * NEE];
        float c1 = bb[(15 - m) * NEE];
        float v0 = c0 * cum;
        cum *= (1.f - c0);
        float v1 = (m < 15) ? c1 * cum : cum;
        cum *= (1.f - c1);
        dst[(size_t)(((17 + m) & 31)) * NEE] = v0;
        dst[(size_t)((16 - m)) * NEE]        = v1;
    }
}

// ---------------------------------------------------------------------------
// Batched MLP layer: Out = bf16(relu(A @ W^T + bias)), A (8192,256) bf16
// ---------------------------------------------------------------------------
__global__ __launch_bounds__(256) void k_mlp(
    const u16* __restrict__ A, const u16* __restrict__ W,
    const float* __restrict__ bias, u16* __restrict__ Out)
{
    __shared__ u16 ot[32 * 264];
    const int g0 = blockIdx.x * 32;
    const int tid = threadIdx.x, lane = tid & 63, w = tid >> 6;
    const int lm = lane & 15, lg = lane >> 4;
    f32x4 acc[4][2];
    #pragma unroll
    for (int c = 0; c < 4; ++c)
        #pragma unroll
        for (int r = 0; r < 2; ++r)
            #pragma unroll
            for (int z = 0; z < 4; ++z) acc[c][r][z] = 0.f;
    #pragma unroll
    for (int ks = 0; ks < 8; ++ks) {
        bf16x8 a0 = *(const bf16x8*)&A[(size_t)(g0 + lm) * 256 + ks * 32 + lg * 8];
        bf16x8 a1 = *(const bf16x8*)&A[(size_t)(g0 + 16 + lm) * 256 + ks * 32 + lg * 8];
        #pragma unroll
        for (int cf = 0; cf < 4; ++cf) {
            const u16* bp = W + (size_t)(w * 64 + cf * 16 + lm) * 256 + ks * 32 + lg * 8;
            bf16x8 b = *(const bf16x8*)bp;
            acc[cf][0] = MFMA(a0, b, acc[cf][0]);
            acc[cf][1] = MFMA(a1, b, acc[cf][1]);
        }
    }
    #pragma unroll
    for (int cf = 0; cf < 4; ++cf) {
        int col = w * 64 + cf * 16 + lm;
        float bs = bias[col];
        #pragma unroll
        for (int rf = 0; rf < 2; ++rf)
            #pragma unroll
            for (int j = 0; j < 4; ++j) {
                int lrow = rf * 16 + lg * 4 + j;
                ot[lrow * 264 + col] = f2bf(fmaxf(acc[cf][rf][j] + bs, 0.f));
            }
    }
    __syncthreads();
    int lrow = tid >> 3, c0 = (tid & 7) * 32;
    const uint4* src = (const uint4*)&ot[lrow * 264 + c0];
    uint4* dst = (uint4*)&Out[(size_t)(g0 + lrow) * 256 + c0];
    dst[0] = src[0]; dst[1] = src[1]; dst[2] = src[2]; dst[3] = src[3];
}

// ---------------------------------------------------------------------------
// Heads: 25 logits per row + softmaxes + v + p_probs
// ---------------------------------------------------------------------------
__global__ __launch_bounds__(256) void k_heads(
    const u16* __restrict__ zbf,
    const float* __restrict__ aw, const float* __restrict__ ab,
    const float* __restrict__ ow, const float* __restrict__ ob,
    const float* __restrict__ cw, const float* __restrict__ cb,
    const float* __restrict__ P_final, const int* __restrict__ w_used,
    float* __restrict__ out)
{
    __shared__ float zt[32 * 258];
    __shared__ float hd[32][28];
    __shared__ float o8[32][8];
    __shared__ int   wv[32];
    const int g0 = blockIdx.x * 32, tid = threadIdx.x;
    {
        int lrow = tid >> 3, c0 = (tid & 7) * 32;
        const u16* src = &zbf[(size_t)(g0 + lrow) * 256 + c0];
        #pragma unroll
        for (int k = 0; k < 32; ++k) zt[lrow * 258 + c0 + k] = bf2f(src[k]);
    }
    if (tid < 32) wv[tid] = w_used[g0 + tid];
    __syncthreads();
    {
        int r = tid >> 3, s = tid & 7;
        const float* z = &zt[r * 258];
        float a1 = ab[s], a2 = ab[8 + s], a3 = ob[s], a4 = cb[0];
        const float* w1 = aw + s * 256;
        const float* w2_ = aw + (8 + s) * 256;
        const float* w3 = ow + s * 256;
        for (int c = 0; c < 256; ++c) {
            float zv = z[c];
            a1 += zv * w1[c]; a2 += zv * w2_[c]; a3 += zv * w3[c]; a4 += zv * cw[c];
        }
        hd[r][s] = a1; hd[r][8 + s] = a2; hd[r][16 + s] = a3;
        if (s == 0) hd[r][24] = a4;
    }
    __syncthreads();
    if (tid < 32) {
        int r = tid; int g = g0 + r;
        float* orow = out + (size_t)g * OW;
        float mx = hd[r][0];
        #pragma unroll
        for (int k = 1; k < 16; ++k) mx = fmaxf(mx, hd[r][k]);
        float ex[16], ssum = 0.f;
        #pragma unroll
        for (int k = 0; k < 16; ++k) { ex[k] = __expf(hd[r][k] - mx); ssum += ex[k]; }
        float inv = 1.f / ssum;
        #pragma unroll
        for (int k = 0; k < 16; ++k) orow[260 + k] = ex[k] * inv;
        orow[3] = hd[r][24];
        float mo = hd[r][16];
        #pragma unroll
        for (int k = 1; k < 8; ++k) mo = fmaxf(mo, hd[r][16 + k]);
        float eo[8], so = 0.f;
        #pragma unroll
        for (int k = 0; k < 8; ++k) { eo[k] = __expf(hd[r][16 + k] - mo); so += eo[k]; }
        float invo = 1.f / so;
        #pragma unroll
        for (int k = 0; k < 8; ++k) o8[r][k] = eo[k] * invo;
    }
    __syncthreads();
    {
        int r = tid >> 3, kb = tid & 7;
        int g = g0 + r, n = g & 255;
        const float* base = P_final + ((size_t)(wv[r] * NN + n) * 32) * NEE;
        float* orow = out + (size_t)g * OW + 276;
        #pragma unroll
        for (int m = 0; m < 4; ++m) {
            int k = kb + m * 8;
            const float* pe = base + k * NEE;
            float a = 0.f;
            #pragma unroll
            for (int e = 0; e < 8; ++e) a += pe[e] * o8[r][e];
            orow[k] = a;
        }
    }
}

// ---------------------------------------------------------------------------
extern "C" void kernel_launch(void* const* d_in, const int* in_sizes, int n_in,
                              void* d_out, int out_size, void* d_ws, size_t ws_size,
                              hipStream_t stream) {
    const float* condition = (const float*)d_in[0];
    const int*   lines     = (const int*)  d_in[1];
    const int*   actions   = (const int*)  d_in[2];
    const float* h0        = (const float*)d_in[3];
    const int*   w0        = (const int*)  d_in[4];
    const float* embed     = (const float*)d_in[5];
    const float* gwih_f    = (const float*)d_in[6];
    const float* gwhh_f    = (const float*)d_in[7];
    const float* gbih_f    = (const float*)d_in[8];
    const float* gbhh_f    = (const float*)d_in[9];
    const float* gwih_b    = (const float*)d_in[10];
    const float* gwhh_b    = (const float*)d_in[11];
    const float* gbih_b    = (const float*)d_in[12];
    const float* gbhh_b    = (const float*)d_in[13];
    const float* w2        = (const float*)d_in[14];
    const float* b2        = (const float*)d_in[15];
    const float* cwih      = (const float*)d_in[16];
    const float* cwhh      = (const float*)d_in[17];
    const float* cbih      = (const float*)d_in[18];
    const float* cbhh      = (const float*)d_in[19];
    const float* mw1       = (const float*)d_in[20];
    const float* mb1       = (const float*)d_in[21];
    const float* mw2       = (const float*)d_in[22];
    const float* mb2       = (const float*)d_in[23];
    const float* ow        = (const float*)d_in[24];
    const float* ob        = (const float*)d_in[25];
    const float* aw        = (const float*)d_in[26];
    const float* ab        = (const float*)d_in[27];
    const float* cw        = (const float*)d_in[28];
    const float* cb        = (const float*)d_in[29];
    float* out = (float*)d_out;

    // workspace carve-up (~23 MB, aliased)
    char* base = (char*)d_ws;
    auto alloc = [&](size_t bytes) { char* r = base; base += (bytes + 255) & ~(size_t)255; return r; };
    u16*   gif_tok = (u16*)alloc(64 * H3 * 2);
    u16*   gib_tok = (u16*)alloc(64 * H3 * 2);
    u16*   gic_tok = (u16*)alloc(64 * H3 * 2);
    u16*   whhr_f  = (u16*)alloc(H3 * 256 * 2);
    u16*   whhr_b  = (u16*)alloc(H3 * 256 * 2);
    u16*   cwhr    = (u16*)alloc(H3 * 256 * 2);
    u16*   mw1bf   = (u16*)alloc(256 * 256 * 2);
    u16*   mw2bf   = (u16*)alloc(256 * 256 * 2);
    u16*   w2bf    = (u16*)alloc(16 * 256 * 2);
    u16*   cwcbf   = (u16*)alloc(H3 * 64 * 2);
    u16*   gi_full = (u16*)alloc((size_t)TT * NN * H3 * 2);   // 12.6 MB
    float* Bf      = (float*)alloc((size_t)16 * 256 * 16 * 8 * 4);
    float* Bb      = (float*)alloc((size_t)16 * 256 * 16 * 8 * 4);
    u16*   Hallbf  = (u16*)alloc((size_t)TT * NN * 256 * 2);
    int*   w_used  = (int*)alloc((size_t)TT * NN * 4);
    int*   tok_used= (int*)alloc((size_t)TT * NN * 4);
    // aliases (dead-after-ctrl / dead-after-stick regions)
    float* P_final = (float*)gi_full;                          // written post-ctrl
    u16*   zbf     = (u16*)((char*)gi_full + (size_t)4 * 1024 * 1024);
    u16*   z1bf    = (u16*)Bf;                                 // after k_stick

    k_prep<<<3024, 256, 0, stream>>>(gwhh_f, gwhh_b, cwhh, mw1, mw2, w2, cwih,
                                     whhr_f, whhr_b, cwhr, mw1bf, mw2bf, w2bf, cwcbf);

    k_tok<<<18, 256, 0, stream>>>(embed,
                                  gwih_f, gbih_f, gbhh_f,
                                  gwih_b, gbih_b, gbhh_b,
                                  cwih, cbih, cbhh,
                                  gif_tok, gib_tok, gic_tok);

    k_wtraj<<<1, 256, 0, stream>>>(actions, w0, lines, out, w_used, tok_used);

    k_cg<<<256, 256, 0, stream>>>(condition, cwcbf, gic_tok, tok_used, gi_full);

    k_gru<<<128, 512, 0, stream>>>(whhr_f, whhr_b, gif_tok, gib_tok, gbhh_f, gbhh_b,
                                   w2bf, b2, Bf, Bb, lines);

    k_ctrl<<<4, 512, 0, stream>>>(cwhr, gi_full, cbhh, h0, Hallbf, out);

    k_stick<<<128, 256, 0, stream>>>(Bf, Bb, P_final);

    k_mlp<<<256, 256, 0, stream>>>(Hallbf, mw1bf, mb1, z1bf);
    k_mlp<<<256, 256, 0, stream>>>(z1bf, mw2bf, mb2, zbf);

    k_heads<<<256, 256, 0, stream>>>(zbf, aw, ab, ow, ob, cw, cb, P_final, w_used, out);
}